// Round 1
// baseline (1105.609 us; speedup 1.0000x reference)
//
#include <hip/hip_runtime.h>
#include <hip/hip_bf16.h>
#include <cstdint>
#include <cstddef>

// VQKD forward: z = l2norm(tanh(X@W1+b1)@W2+b2); idx = argmin_k ||z-emb_k||^2 with
// emb = l2norm(codebook); z_q = emb[idx] (straight-through); loss = mean((emb[idx]-z)^2).
// All fp32 (bf16 MFMA would flip argmin near-ties vs the numpy reference).

namespace {
constexpr int TOKENS = 8 * 4096;   // 32768
constexpr int DENC   = 768;
constexpr int DC     = 32;
constexpr int KC     = 8192;
constexpr int BM = 128, BN = 128, BK = 16;
constexpr int CHUNK  = 512;        // codes staged in LDS per search block
}

// ---------- K1: normalize codebook rows, store emb_n and e2 = sum(emb_n^2) ----------
__global__ void knorm_codes(const float* __restrict__ cb,
                            float* __restrict__ embn, float* __restrict__ e2) {
  int t = blockIdx.x * blockDim.x + threadIdx.x;      // KC*DC threads
  int k = t >> 5, c = t & 31;
  float v = cb[(size_t)k * DC + c];
  float ss = v * v;
  #pragma unroll
  for (int m = 16; m >= 1; m >>= 1) ss += __shfl_xor(ss, m, 32);
  float nrm = fmaxf(sqrtf(ss), 1e-12f);
  float vn = v / nrm;
  embn[(size_t)k * DC + c] = vn;
  float s2 = vn * vn;
  #pragma unroll
  for (int m = 16; m >= 1; m >>= 1) s2 += __shfl_xor(s2, m, 32);
  if (c == 0) e2[k] = s2;
}

// ---------- K2: H = tanh(X @ W1 + b1), fp32 tiled GEMM 128x128, 8x8 micro ----------
__global__ __launch_bounds__(256, 4)
void kgemm1(const float* __restrict__ X, const float* __restrict__ W1,
            const float* __restrict__ bias1, float* __restrict__ H) {
  __shared__ float As[BK][BM];   // A staged transposed: As[k][m]
  __shared__ float Bs[BK][BN];
  const int m0 = blockIdx.x * BM;
  const int n0 = blockIdx.y * BN;
  const int t  = threadIdx.x;
  const int tx = t & 15, ty = t >> 4;

  // A-load granule: 128 rows x 4 float4-cols; thread t covers rows t>>2 and (t>>2)+64
  const int arow = t >> 2;
  const int ac4  = (t & 3) * 4;
  // B-load granule: 16 rows x 32 float4-cols; thread t covers rows t>>5 and (t>>5)+8
  const int brow = t >> 5;
  const int bc4  = (t & 31) * 4;

  float acc[8][8] = {};
  const float* Xp = X + (size_t)m0 * DENC;

  for (int k0 = 0; k0 < DENC; k0 += BK) {
    float4 a0 = *(const float4*)&Xp[(size_t)arow        * DENC + k0 + ac4];
    float4 a1 = *(const float4*)&Xp[(size_t)(arow + 64) * DENC + k0 + ac4];
    float4 b0 = *(const float4*)&W1[(size_t)(k0 + brow)     * DENC + n0 + bc4];
    float4 b1 = *(const float4*)&W1[(size_t)(k0 + brow + 8) * DENC + n0 + bc4];
    __syncthreads();   // previous iteration's LDS reads done
    As[ac4 + 0][arow] = a0.x; As[ac4 + 1][arow] = a0.y;
    As[ac4 + 2][arow] = a0.z; As[ac4 + 3][arow] = a0.w;
    As[ac4 + 0][arow + 64] = a1.x; As[ac4 + 1][arow + 64] = a1.y;
    As[ac4 + 2][arow + 64] = a1.z; As[ac4 + 3][arow + 64] = a1.w;
    *(float4*)&Bs[brow][bc4]     = b0;
    *(float4*)&Bs[brow + 8][bc4] = b1;
    __syncthreads();
    #pragma unroll
    for (int kk = 0; kk < BK; ++kk) {
      float av[8], bv[8];
      *(float4*)&av[0] = *(const float4*)&As[kk][ty * 8];
      *(float4*)&av[4] = *(const float4*)&As[kk][ty * 8 + 4];
      *(float4*)&bv[0] = *(const float4*)&Bs[kk][tx * 8];
      *(float4*)&bv[4] = *(const float4*)&Bs[kk][tx * 8 + 4];
      #pragma unroll
      for (int i = 0; i < 8; ++i)
        #pragma unroll
        for (int j = 0; j < 8; ++j)
          acc[i][j] = fmaf(av[i], bv[j], acc[i][j]);
    }
  }

  float bv8[8];
  #pragma unroll
  for (int j = 0; j < 8; ++j) bv8[j] = bias1[n0 + tx * 8 + j];
  #pragma unroll
  for (int i = 0; i < 8; ++i) {
    float o[8];
    #pragma unroll
    for (int j = 0; j < 8; ++j) o[j] = tanhf(acc[i][j] + bv8[j]);
    size_t off = (size_t)(m0 + ty * 8 + i) * DENC + n0 + tx * 8;
    *(float4*)&H[off]     = *(float4*)&o[0];
    *(float4*)&H[off + 4] = *(float4*)&o[4];
  }
}

// ---------- K3: z = H @ W2 + b2, then l2-normalize rows -> zn ----------
__global__ void kgemm2(const float* __restrict__ H, const float* __restrict__ W2,
                       const float* __restrict__ b2, float* __restrict__ zn) {
  int t = blockIdx.x * blockDim.x + threadIdx.x;   // TOKENS*DC threads
  int tok = t >> 5, c = t & 31;
  const float* h = H + (size_t)tok * DENC;
  float a0 = 0.f, a1 = 0.f, a2 = 0.f, a3 = 0.f;
  for (int k = 0; k < DENC; k += 4) {
    float4 hv = *(const float4*)&h[k];
    a0 = fmaf(hv.x, W2[(size_t)(k + 0) * DC + c], a0);
    a1 = fmaf(hv.y, W2[(size_t)(k + 1) * DC + c], a1);
    a2 = fmaf(hv.z, W2[(size_t)(k + 2) * DC + c], a2);
    a3 = fmaf(hv.w, W2[(size_t)(k + 3) * DC + c], a3);
  }
  float z = ((a0 + a1) + (a2 + a3)) + b2[c];
  float ss = z * z;
  #pragma unroll
  for (int m = 16; m >= 1; m >>= 1) ss += __shfl_xor(ss, m, 32);
  float nrm = fmaxf(sqrtf(ss), 1e-12f);
  zn[t] = z / nrm;
}

__device__ inline unsigned long long packkey(float d, int idx) {
  unsigned int u = __float_as_uint(d);
  u = (u & 0x80000000u) ? ~u : (u | 0x80000000u);   // monotone float->uint
  return ((unsigned long long)u << 32) | (unsigned int)idx;
}

// ---------- K4: nearest code; chunk-parallel, merged via atomicMin on packed key ----------
__global__ __launch_bounds__(256)
void ksearch(const float* __restrict__ zn, const float* __restrict__ embn,
             const float* __restrict__ e2, unsigned long long* __restrict__ keys) {
  __shared__ float cs[CHUNK][DC];    // 64 KB
  __shared__ float ce2[CHUNK];
  const int k0 = blockIdx.x * CHUNK;
  const int t  = threadIdx.x;

  const float4* src = (const float4*)(embn + (size_t)k0 * DC);
  float4* dst = (float4*)&cs[0][0];
  for (int i = t; i < CHUNK * DC / 4; i += 256) dst[i] = src[i];
  for (int i = t; i < CHUNK; i += 256) ce2[i] = e2[k0 + i];

  const int ta = blockIdx.y * 512 + t;
  const int tb = ta + 256;
  float za[32], zb[32];
  #pragma unroll
  for (int i = 0; i < 8; ++i) {
    *(float4*)&za[i * 4] = *(const float4*)&zn[(size_t)ta * DC + i * 4];
    *(float4*)&zb[i * 4] = *(const float4*)&zn[(size_t)tb * DC + i * 4];
  }
  __syncthreads();

  float bda = 1e30f, bdb = 1e30f;
  int   bia = 0,     bib = 0;
  for (int cc = 0; cc < CHUNK; ++cc) {
    float p0 = 0.f, p1 = 0.f, p2 = 0.f, p3 = 0.f;
    float q0 = 0.f, q1 = 0.f, q2 = 0.f, q3 = 0.f;
    #pragma unroll
    for (int c = 0; c < DC; c += 4) {
      float4 cv = *(const float4*)&cs[cc][c];
      p0 = fmaf(za[c + 0], cv.x, p0);
      p1 = fmaf(za[c + 1], cv.y, p1);
      p2 = fmaf(za[c + 2], cv.z, p2);
      p3 = fmaf(za[c + 3], cv.w, p3);
      q0 = fmaf(zb[c + 0], cv.x, q0);
      q1 = fmaf(zb[c + 1], cv.y, q1);
      q2 = fmaf(zb[c + 2], cv.z, q2);
      q3 = fmaf(zb[c + 3], cv.w, q3);
    }
    float e  = ce2[cc];
    float da = fmaf(-2.f, (p0 + p1) + (p2 + p3), e);
    float db = fmaf(-2.f, (q0 + q1) + (q2 + q3), e);
    if (da < bda) { bda = da; bia = k0 + cc; }   // ascending scan: first-min kept
    if (db < bdb) { bdb = db; bib = k0 + cc; }
  }
  atomicMin(&keys[ta], packkey(bda, bia));
  atomicMin(&keys[tb], packkey(bdb, bib));
}

// ---------- K5: gather emb[idx], straight-through z_q, loss, idx-as-float ----------
__global__ void kfinal(const unsigned long long* __restrict__ keys,
                       const float* __restrict__ zn, const float* __restrict__ embn,
                       float* __restrict__ zq, float* __restrict__ loss,
                       float* __restrict__ oidx) {
  int t = blockIdx.x * blockDim.x + threadIdx.x;   // TOKENS*DC threads
  int tok = t >> 5, c = t & 31;
  unsigned long long key = keys[tok];
  int idx = (int)(unsigned int)(key & 0xFFFFFFFFull);
  float q = embn[(size_t)idx * DC + c];
  float z = zn[t];
  zq[t] = z + (q - z);                 // == q up to 1 ulp; mimics the reference formula
  float d = q - z;
  float ss = d * d;
  #pragma unroll
  for (int m = 16; m >= 1; m >>= 1) ss += __shfl_xor(ss, m, 32);
  if (c == 0) {
    atomicAdd(loss, ss * (1.0f / (float)(TOKENS * DC)));   // BETA = 1
    oidx[tok] = (float)idx;
  }
}

extern "C" void kernel_launch(void* const* d_in, const int* in_sizes, int n_in,
                              void* d_out, int out_size, void* d_ws, size_t ws_size,
                              hipStream_t stream) {
  const float* X   = (const float*)d_in[0];
  const float* W1  = (const float*)d_in[1];
  const float* B1  = (const float*)d_in[2];
  const float* W2  = (const float*)d_in[3];
  const float* B2  = (const float*)d_in[4];
  const float* CB  = (const float*)d_in[5];

  float* out  = (float*)d_out;
  float* zq   = out;                          // TOKENS*DC
  float* loss = out + (size_t)TOKENS * DC;    // 1
  float* oidx = loss + 1;                     // TOKENS (written as float)

  char* ws = (char*)d_ws;
  size_t off = 0;
  float* H    = (float*)(ws + off); off += (size_t)TOKENS * DENC * 4;   // 96 MB
  float* zn   = (float*)(ws + off); off += (size_t)TOKENS * DC * 4;     // 4 MB
  float* embn = (float*)(ws + off); off += (size_t)KC * DC * 4;         // 1 MB
  float* e2   = (float*)(ws + off); off += (size_t)KC * 4;              // 32 KB
  unsigned long long* keys = (unsigned long long*)(ws + off);           // 256 KB
  // total ~101.3 MB of d_ws required

  hipMemsetAsync(loss, 0, sizeof(float), stream);
  hipMemsetAsync(keys, 0xFF, (size_t)TOKENS * 8, stream);   // key = +inf sentinel

  knorm_codes<<<(KC * DC) / 256, 256, 0, stream>>>(CB, embn, e2);
  kgemm1<<<dim3(TOKENS / BM, DENC / BN), 256, 0, stream>>>(X, W1, B1, H);
  kgemm2<<<(TOKENS * DC) / 256, 256, 0, stream>>>(H, W2, B2, zn);
  ksearch<<<dim3(KC / CHUNK, TOKENS / 512), 256, 0, stream>>>(zn, embn, e2, keys);
  kfinal<<<(TOKENS * DC) / 256, 256, 0, stream>>>(keys, zn, embn, zq, loss, oidx);
}

// Round 2
// 932.007 us; speedup vs baseline: 1.1863x; 1.1863x over previous
//
#include <hip/hip_runtime.h>
#include <hip/hip_bf16.h>
#include <cstdint>
#include <cstddef>

// VQKD forward: z = l2norm(tanh(X@W1+b1)@W2+b2); idx = argmin_k ||z-emb_k||^2 with
// emb = l2norm(codebook); z_q = emb[idx] (straight-through); loss = mean((emb[idx]-z)^2).
// All fp32 (bf16 MFMA would flip argmin near-ties vs the numpy reference).

namespace {
constexpr int TOKENS = 8 * 4096;   // 32768
constexpr int DENC   = 768;
constexpr int DC     = 32;
constexpr int KC     = 8192;
constexpr int BM = 128, BN = 128, BK = 16;
constexpr int LDA = BM + 4;        // 132: pad so staging writes are 2-way (free), reads aligned
constexpr int LDB = BN + 4;
constexpr int CHUNK  = 512;        // codes staged in LDS per search block
}

// ---------- K1: normalize codebook rows, store emb_n and e2 = sum(emb_n^2) ----------
__global__ void knorm_codes(const float* __restrict__ cb,
                            float* __restrict__ embn, float* __restrict__ e2) {
  int t = blockIdx.x * blockDim.x + threadIdx.x;      // KC*DC threads
  int k = t >> 5, c = t & 31;
  float v = cb[(size_t)k * DC + c];
  float ss = v * v;
  #pragma unroll
  for (int m = 16; m >= 1; m >>= 1) ss += __shfl_xor(ss, m, 32);
  float nrm = fmaxf(sqrtf(ss), 1e-12f);
  float vn = v / nrm;
  embn[(size_t)k * DC + c] = vn;
  float s2 = vn * vn;
  #pragma unroll
  for (int m = 16; m >= 1; m >>= 1) s2 += __shfl_xor(s2, m, 32);
  if (c == 0) e2[k] = s2;
}

// ---------- K2: H = tanh(X @ W1 + b1), fp32 tiled GEMM 128x128, 8x8 micro ----------
// grid = (N/BN = 6, M/BM = 256): x-fastest dispatch keeps the 6 blocks sharing an
// X-panel temporally adjacent (L2/L3 reuse). Micro-tile split {q*4, 64+q*4} kills
// the 4-way LDS read conflict of the old {q*8} layout.
__global__ __launch_bounds__(256, 4)
void kgemm1(const float* __restrict__ X, const float* __restrict__ W1,
            const float* __restrict__ bias1, float* __restrict__ H) {
  __shared__ float As[BK][LDA];   // A staged transposed: As[k][m]
  __shared__ float Bs[BK][LDB];
  const int n0 = blockIdx.x * BN;
  const int m0 = blockIdx.y * BM;
  const int t  = threadIdx.x;
  const int tx = t & 15, ty = t >> 4;

  // A-load granule: 128 rows x 4 float4-cols; thread t covers rows t>>2 and (t>>2)+64
  const int arow = t >> 2;
  const int ac4  = (t & 3) * 4;
  // B-load granule: 16 rows x 32 float4-cols; thread t covers rows t>>5 and (t>>5)+8
  const int brow = t >> 5;
  const int bc4  = (t & 31) * 4;

  float acc[8][8] = {};
  const float* Xp = X + (size_t)m0 * DENC;

  for (int k0 = 0; k0 < DENC; k0 += BK) {
    float4 a0 = *(const float4*)&Xp[(size_t)arow        * DENC + k0 + ac4];
    float4 a1 = *(const float4*)&Xp[(size_t)(arow + 64) * DENC + k0 + ac4];
    float4 b0 = *(const float4*)&W1[(size_t)(k0 + brow)     * DENC + n0 + bc4];
    float4 b1 = *(const float4*)&W1[(size_t)(k0 + brow + 8) * DENC + n0 + bc4];
    __syncthreads();   // previous iteration's LDS reads done
    As[ac4 + 0][arow] = a0.x; As[ac4 + 1][arow] = a0.y;
    As[ac4 + 2][arow] = a0.z; As[ac4 + 3][arow] = a0.w;
    As[ac4 + 0][arow + 64] = a1.x; As[ac4 + 1][arow + 64] = a1.y;
    As[ac4 + 2][arow + 64] = a1.z; As[ac4 + 3][arow + 64] = a1.w;
    *(float4*)&Bs[brow][bc4]     = b0;
    *(float4*)&Bs[brow + 8][bc4] = b1;
    __syncthreads();
    #pragma unroll
    for (int kk = 0; kk < BK; ++kk) {
      float av[8], bv[8];
      *(float4*)&av[0] = *(const float4*)&As[kk][ty * 4];        // banks 4*ty: conflict-free
      *(float4*)&av[4] = *(const float4*)&As[kk][64 + ty * 4];
      *(float4*)&bv[0] = *(const float4*)&Bs[kk][tx * 4];        // banks 4*tx: 2-way (free)
      *(float4*)&bv[4] = *(const float4*)&Bs[kk][64 + tx * 4];
      #pragma unroll
      for (int i = 0; i < 8; ++i)
        #pragma unroll
        for (int j = 0; j < 8; ++j)
          acc[i][j] = fmaf(av[i], bv[j], acc[i][j]);
    }
  }

  float bc0[4], bc1[4];
  #pragma unroll
  for (int j = 0; j < 4; ++j) {
    bc0[j] = bias1[n0 + tx * 4 + j];
    bc1[j] = bias1[n0 + 64 + tx * 4 + j];
  }
  #pragma unroll
  for (int i = 0; i < 8; ++i) {
    int row = m0 + ((i < 4) ? (ty * 4 + i) : (64 + ty * 4 + i - 4));
    float o0[4], o1[4];
    #pragma unroll
    for (int j = 0; j < 4; ++j) {
      o0[j] = tanhf(acc[i][j]     + bc0[j]);
      o1[j] = tanhf(acc[i][4 + j] + bc1[j]);
    }
    size_t off = (size_t)row * DENC + n0;
    *(float4*)&H[off + tx * 4]      = *(float4*)&o0[0];
    *(float4*)&H[off + 64 + tx * 4] = *(float4*)&o1[0];
  }
}

// ---------- K3: z = H @ W2 + b2, then l2-normalize rows -> zn ----------
__global__ void kgemm2(const float* __restrict__ H, const float* __restrict__ W2,
                       const float* __restrict__ b2, float* __restrict__ zn) {
  int t = blockIdx.x * blockDim.x + threadIdx.x;   // TOKENS*DC threads
  int tok = t >> 5, c = t & 31;
  const float* h = H + (size_t)tok * DENC;
  float a0 = 0.f, a1 = 0.f, a2 = 0.f, a3 = 0.f;
  for (int k = 0; k < DENC; k += 4) {
    float4 hv = *(const float4*)&h[k];
    a0 = fmaf(hv.x, W2[(size_t)(k + 0) * DC + c], a0);
    a1 = fmaf(hv.y, W2[(size_t)(k + 1) * DC + c], a1);
    a2 = fmaf(hv.z, W2[(size_t)(k + 2) * DC + c], a2);
    a3 = fmaf(hv.w, W2[(size_t)(k + 3) * DC + c], a3);
  }
  float z = ((a0 + a1) + (a2 + a3)) + b2[c];
  float ss = z * z;
  #pragma unroll
  for (int m = 16; m >= 1; m >>= 1) ss += __shfl_xor(ss, m, 32);
  float nrm = fmaxf(sqrtf(ss), 1e-12f);
  zn[t] = z / nrm;
}

__device__ inline unsigned long long packkey(float d, int idx) {
  unsigned int u = __float_as_uint(d);
  u = (u & 0x80000000u) ? ~u : (u | 0x80000000u);   // monotone float->uint
  return ((unsigned long long)u << 32) | (unsigned int)idx;
}

// ---------- K4: nearest code; chunk-parallel, merged via atomicMin on packed key ----------
__global__ __launch_bounds__(256)
void ksearch(const float* __restrict__ zn, const float* __restrict__ embn,
             const float* __restrict__ e2, unsigned long long* __restrict__ keys) {
  __shared__ float cs[CHUNK][DC];    // 64 KB
  __shared__ float ce2[CHUNK];
  const int k0 = blockIdx.x * CHUNK;
  const int t  = threadIdx.x;

  const float4* src = (const float4*)(embn + (size_t)k0 * DC);
  float4* dst = (float4*)&cs[0][0];
  for (int i = t; i < CHUNK * DC / 4; i += 256) dst[i] = src[i];
  for (int i = t; i < CHUNK; i += 256) ce2[i] = e2[k0 + i];

  const int ta = blockIdx.y * 512 + t;
  const int tb = ta + 256;
  float za[32], zb[32];
  #pragma unroll
  for (int i = 0; i < 8; ++i) {
    *(float4*)&za[i * 4] = *(const float4*)&zn[(size_t)ta * DC + i * 4];
    *(float4*)&zb[i * 4] = *(const float4*)&zn[(size_t)tb * DC + i * 4];
  }
  __syncthreads();

  float bda = 1e30f, bdb = 1e30f;
  int   bia = 0,     bib = 0;
  for (int cc = 0; cc < CHUNK; ++cc) {
    float p0 = 0.f, p1 = 0.f, p2 = 0.f, p3 = 0.f;
    float q0 = 0.f, q1 = 0.f, q2 = 0.f, q3 = 0.f;
    #pragma unroll
    for (int c = 0; c < DC; c += 4) {
      float4 cv = *(const float4*)&cs[cc][c];
      p0 = fmaf(za[c + 0], cv.x, p0);
      p1 = fmaf(za[c + 1], cv.y, p1);
      p2 = fmaf(za[c + 2], cv.z, p2);
      p3 = fmaf(za[c + 3], cv.w, p3);
      q0 = fmaf(zb[c + 0], cv.x, q0);
      q1 = fmaf(zb[c + 1], cv.y, q1);
      q2 = fmaf(zb[c + 2], cv.z, q2);
      q3 = fmaf(zb[c + 3], cv.w, q3);
    }
    float e  = ce2[cc];
    float da = fmaf(-2.f, (p0 + p1) + (p2 + p3), e);
    float db = fmaf(-2.f, (q0 + q1) + (q2 + q3), e);
    if (da < bda) { bda = da; bia = k0 + cc; }   // ascending scan: first-min kept
    if (db < bdb) { bdb = db; bib = k0 + cc; }
  }
  atomicMin(&keys[ta], packkey(bda, bia));
  atomicMin(&keys[tb], packkey(bdb, bib));
}

// ---------- K5: gather emb[idx], straight-through z_q, loss, idx-as-float ----------
// 1024 threads = 32 tokens per block; loss reduced in LDS -> ONE atomicAdd per block
// (32 total, vs 32768 same-address atomics before).
__global__ __launch_bounds__(1024)
void kfinal(const unsigned long long* __restrict__ keys,
            const float* __restrict__ zn, const float* __restrict__ embn,
            float* __restrict__ zq, float* __restrict__ loss,
            float* __restrict__ oidx) {
  __shared__ float red[32];
  int t = blockIdx.x * blockDim.x + threadIdx.x;   // TOKENS*DC threads
  int tok = t >> 5, c = t & 31;
  unsigned long long key = keys[tok];
  int idx = (int)(unsigned int)(key & 0xFFFFFFFFull);
  float q = embn[(size_t)idx * DC + c];
  float z = zn[t];
  zq[t] = z + (q - z);                 // == q up to 1 ulp; mimics the reference formula
  float d = q - z;
  float ss = d * d;
  #pragma unroll
  for (int m = 16; m >= 1; m >>= 1) ss += __shfl_xor(ss, m, 32);
  if (c == 0) {
    red[threadIdx.x >> 5] = ss;
    oidx[tok] = (float)idx;
  }
  __syncthreads();
  if (threadIdx.x < 32) {
    float v = red[threadIdx.x];
    #pragma unroll
    for (int m = 16; m >= 1; m >>= 1) v += __shfl_xor(v, m, 32);
    if (threadIdx.x == 0)
      atomicAdd(loss, v * (1.0f / (float)(TOKENS * DC)));   // BETA = 1
  }
}

extern "C" void kernel_launch(void* const* d_in, const int* in_sizes, int n_in,
                              void* d_out, int out_size, void* d_ws, size_t ws_size,
                              hipStream_t stream) {
  const float* X   = (const float*)d_in[0];
  const float* W1  = (const float*)d_in[1];
  const float* B1  = (const float*)d_in[2];
  const float* W2  = (const float*)d_in[3];
  const float* B2  = (const float*)d_in[4];
  const float* CB  = (const float*)d_in[5];

  float* out  = (float*)d_out;
  float* zq   = out;                          // TOKENS*DC
  float* loss = out + (size_t)TOKENS * DC;    // 1
  float* oidx = loss + 1;                     // TOKENS (written as float)

  char* ws = (char*)d_ws;
  size_t off = 0;
  float* H    = (float*)(ws + off); off += (size_t)TOKENS * DENC * 4;   // 96 MB
  float* zn   = (float*)(ws + off); off += (size_t)TOKENS * DC * 4;     // 4 MB
  float* embn = (float*)(ws + off); off += (size_t)KC * DC * 4;         // 1 MB
  float* e2   = (float*)(ws + off); off += (size_t)KC * 4;              // 32 KB
  unsigned long long* keys = (unsigned long long*)(ws + off);           // 256 KB
  // total ~101.3 MB of d_ws required

  hipMemsetAsync(loss, 0, sizeof(float), stream);
  hipMemsetAsync(keys, 0xFF, (size_t)TOKENS * 8, stream);   // key = +inf sentinel

  knorm_codes<<<(KC * DC) / 256, 256, 0, stream>>>(CB, embn, e2);
  kgemm1<<<dim3(DENC / BN, TOKENS / BM), 256, 0, stream>>>(X, W1, B1, H);
  kgemm2<<<(TOKENS * DC) / 256, 256, 0, stream>>>(H, W2, B2, zn);
  ksearch<<<dim3(KC / CHUNK, TOKENS / 512), 256, 0, stream>>>(zn, embn, e2, keys);
  kfinal<<<TOKENS * DC / 1024, 1024, 0, stream>>>(keys, zn, embn, zq, loss, oidx);
}

// Round 3
// 636.882 us; speedup vs baseline: 1.7360x; 1.4634x over previous
//
#include <hip/hip_runtime.h>
#include <hip/hip_bf16.h>
#include <cstdint>
#include <cstddef>

// VQKD forward: z = l2norm(tanh(X@W1+b1)@W2+b2); idx = argmin_k ||z-emb_k||^2 with
// emb = l2norm(codebook); z_q = emb[idx]; loss = mean((emb[idx]-z)^2).
// GEMM1 runs on f16 matrix cores with 2-way fp32 split (xh+xl)(wh+wl), 3 products:
// relative error ~3*2^-22 — same order as an fp32 FMA chain -> argmin-safe.

namespace {
constexpr int TOKENS = 8 * 4096;   // 32768
constexpr int DENC   = 768;
constexpr int DC     = 32;
constexpr int KC     = 8192;
constexpr int BM = 128, BN = 128, BK = 64;   // MFMA tile for GEMM1
constexpr int CHUNK  = 512;        // codes staged in LDS per search block
constexpr float WSCALE = 1024.0f;  // keeps w_lo out of fp16 subnormals
}

typedef _Float16 f16x8 __attribute__((ext_vector_type(8)));
typedef float    f32x4 __attribute__((ext_vector_type(4)));

__device__ inline void split2(float v, _Float16& h, _Float16& l) {
  h = (_Float16)v;
  l = (_Float16)(v - (float)h);
}

// ---------- K0: split W1 (scaled) into fp16 hi/lo, TRANSPOSED to [N][K] ----------
__global__ void ksplitW(const float* __restrict__ W1,
                        _Float16* __restrict__ Wh, _Float16* __restrict__ Wl) {
  int n = blockIdx.y;                               // 768
  int k = blockIdx.x * 256 + threadIdx.x;           // 768
  float w = W1[(size_t)k * DENC + n] * WSCALE;      // strided read (L2-resident)
  _Float16 h, l; split2(w, h, l);
  Wh[(size_t)n * DENC + k] = h;                     // coalesced write
  Wl[(size_t)n * DENC + k] = l;
}

// ---------- K1: normalize codebook rows, store emb_n and e2 = sum(emb_n^2) ----------
__global__ void knorm_codes(const float* __restrict__ cb,
                            float* __restrict__ embn, float* __restrict__ e2) {
  int t = blockIdx.x * blockDim.x + threadIdx.x;      // KC*DC threads
  int k = t >> 5, c = t & 31;
  float v = cb[(size_t)k * DC + c];
  float ss = v * v;
  #pragma unroll
  for (int m = 16; m >= 1; m >>= 1) ss += __shfl_xor(ss, m, 32);
  float nrm = fmaxf(sqrtf(ss), 1e-12f);
  float vn = v / nrm;
  embn[(size_t)k * DC + c] = vn;
  float s2 = vn * vn;
  #pragma unroll
  for (int m = 16; m >= 1; m >>= 1) s2 += __shfl_xor(s2, m, 32);
  if (c == 0) e2[k] = s2;
}

// ---------- K2: H = tanh(X @ W1 + b1) via MFMA f16 split-2 (3 passes) ----------
// 128x128 tile, BK=64, 4 waves (2x2), wave-tile 64x64 = 4x4 frags of 16x16x32.
// LDS layout [k-octet][row][8]: fragment reads AND staging writes are uniform
// 8-round bank patterns (conflict-free). XCD-chunked swizzle: each XCD owns a
// contiguous 32-M-tile range so the fp32 X panel is HBM-fetched exactly once.
__global__ __launch_bounds__(256, 2)
void kgemm1(const float* __restrict__ X,
            const _Float16* __restrict__ Wh, const _Float16* __restrict__ Wl,
            const float* __restrict__ bias1, float* __restrict__ H) {
  __shared__ __align__(16) _Float16 Ah[8][BM][8], Al[8][BM][8];  // 16 KB each
  __shared__ __align__(16) _Float16 Bh[8][BN][8], Bl[8][BN][8];  // total 64 KB

  // XCD-aware bijective swizzle (1536 = 8 XCD * 192; 192 = 32 M-tiles * 6 N-tiles)
  const int bid = blockIdx.x;
  const int xcd = bid & 7;
  const int w   = bid >> 3;            // 0..191
  const int n_t = w % 6;
  const int m_t = xcd * 32 + w / 6;
  const int m0 = m_t * BM, n0 = n_t * BN;

  const int t    = threadIdx.x;
  const int lane = t & 63;
  const int wv   = t >> 6;
  const int wm   = wv >> 1, wn = wv & 1;
  const int lrow = lane & 15;
  const int lgrp = lane >> 4;          // 0..3 -> k-octet within a 32-k slice

  // A staging: thread covers row (t&127), k-octets g*4..g*4+3 (g = t>>7)
  const int arow = t & 127;
  const int ag   = t >> 7;
  // B staging: thread covers col (t&127) of array (t>>7): 0=hi, 1=lo
  const int bcol = t & 127;
  const int barr = t >> 7;

  const float*    xp = X  + (size_t)(m0 + arow) * DENC + ag * 32;
  const _Float16* wp = (barr ? Wl : Wh) + (size_t)(n0 + bcol) * DENC;

  f32x4 acc[4][4];
  #pragma unroll
  for (int i = 0; i < 4; ++i)
    #pragma unroll
    for (int j = 0; j < 4; ++j) acc[i][j] = (f32x4)0.0f;

  float4 pa[8];   // prefetched A: 4 k-octets x 2 float4
  f16x8  pb[8];   // prefetched B: 8 k-octets x 16B

  #pragma unroll
  for (int j = 0; j < 4; ++j) {
    pa[2*j]   = *(const float4*)&xp[j * 8];
    pa[2*j+1] = *(const float4*)&xp[j * 8 + 4];
  }
  #pragma unroll
  for (int j = 0; j < 8; ++j) pb[j] = *(const f16x8*)&wp[j * 8];

  for (int step = 0; step < DENC / BK; ++step) {
    __syncthreads();   // prior compute's LDS reads complete
    #pragma unroll
    for (int j = 0; j < 4; ++j) {
      float v[8] = { pa[2*j].x, pa[2*j].y, pa[2*j].z, pa[2*j].w,
                     pa[2*j+1].x, pa[2*j+1].y, pa[2*j+1].z, pa[2*j+1].w };
      f16x8 hh, ll;
      #pragma unroll
      for (int e = 0; e < 8; ++e) { _Float16 h, l; split2(v[e], h, l); hh[e] = h; ll[e] = l; }
      *(f16x8*)&Ah[ag * 4 + j][arow][0] = hh;
      *(f16x8*)&Al[ag * 4 + j][arow][0] = ll;
    }
    {
      _Float16 (*Bd)[BN][8] = barr ? Bl : Bh;
      #pragma unroll
      for (int j = 0; j < 8; ++j) *(f16x8*)&Bd[j][bcol][0] = pb[j];
    }
    __syncthreads();

    if (step < DENC / BK - 1) {        // prefetch next step BEFORE compute
      xp += BK; wp += BK;
      #pragma unroll
      for (int j = 0; j < 4; ++j) {
        pa[2*j]   = *(const float4*)&xp[j * 8];
        pa[2*j+1] = *(const float4*)&xp[j * 8 + 4];
      }
      #pragma unroll
      for (int j = 0; j < 8; ++j) pb[j] = *(const f16x8*)&wp[j * 8];
    }

    #pragma unroll
    for (int s = 0; s < 2; ++s) {      // two 32-k slices per BK=64
      const int ko = s * 4 + lgrp;
      f16x8 nbh[4], nbl[4];
      #pragma unroll
      for (int nf = 0; nf < 4; ++nf) {
        const int col = wn * 64 + nf * 16 + lrow;
        nbh[nf] = *(const f16x8*)&Bh[ko][col][0];
        nbl[nf] = *(const f16x8*)&Bl[ko][col][0];
      }
      #pragma unroll
      for (int mf = 0; mf < 4; ++mf) {
        const int row = wm * 64 + mf * 16 + lrow;
        f16x8 mah = *(const f16x8*)&Ah[ko][row][0];
        f16x8 mal = *(const f16x8*)&Al[ko][row][0];
        #pragma unroll
        for (int nf = 0; nf < 4; ++nf) {
          acc[mf][nf] = __builtin_amdgcn_mfma_f32_16x16x32_f16(mah, nbh[nf], acc[mf][nf], 0, 0, 0);
          acc[mf][nf] = __builtin_amdgcn_mfma_f32_16x16x32_f16(mah, nbl[nf], acc[mf][nf], 0, 0, 0);
          acc[mf][nf] = __builtin_amdgcn_mfma_f32_16x16x32_f16(mal, nbh[nf], acc[mf][nf], 0, 0, 0);
        }
      }
    }
  }

  // Epilogue: un-scale, bias, tanh, store. D layout: row=(lane>>4)*4+r, col=lane&15.
  #pragma unroll
  for (int nf = 0; nf < 4; ++nf) {
    const int col = n0 + wn * 64 + nf * 16 + lrow;
    const float b = bias1[col];
    #pragma unroll
    for (int mf = 0; mf < 4; ++mf) {
      #pragma unroll
      for (int r = 0; r < 4; ++r) {
        const int row = m0 + wm * 64 + mf * 16 + lgrp * 4 + r;
        H[(size_t)row * DENC + col] = tanhf(acc[mf][nf][r] * (1.0f / WSCALE) + b);
      }
    }
  }
}

// ---------- K3: z = H @ W2 + b2, then l2-normalize rows -> zn ----------
__global__ void kgemm2(const float* __restrict__ H, const float* __restrict__ W2,
                       const float* __restrict__ b2, float* __restrict__ zn) {
  int t = blockIdx.x * blockDim.x + threadIdx.x;   // TOKENS*DC threads
  int tok = t >> 5, c = t & 31;
  const float* h = H + (size_t)tok * DENC;
  float a0 = 0.f, a1 = 0.f, a2 = 0.f, a3 = 0.f;
  for (int k = 0; k < DENC; k += 4) {
    float4 hv = *(const float4*)&h[k];
    a0 = fmaf(hv.x, W2[(size_t)(k + 0) * DC + c], a0);
    a1 = fmaf(hv.y, W2[(size_t)(k + 1) * DC + c], a1);
    a2 = fmaf(hv.z, W2[(size_t)(k + 2) * DC + c], a2);
    a3 = fmaf(hv.w, W2[(size_t)(k + 3) * DC + c], a3);
  }
  float z = ((a0 + a1) + (a2 + a3)) + b2[c];
  float ss = z * z;
  #pragma unroll
  for (int m = 16; m >= 1; m >>= 1) ss += __shfl_xor(ss, m, 32);
  float nrm = fmaxf(sqrtf(ss), 1e-12f);
  zn[t] = z / nrm;
}

__device__ inline unsigned long long packkey(float d, int idx) {
  unsigned int u = __float_as_uint(d);
  u = (u & 0x80000000u) ? ~u : (u | 0x80000000u);   // monotone float->uint
  return ((unsigned long long)u << 32) | (unsigned int)idx;
}

// ---------- K4: nearest code; chunk-parallel, merged via atomicMin on packed key ----------
__global__ __launch_bounds__(256)
void ksearch(const float* __restrict__ zn, const float* __restrict__ embn,
             const float* __restrict__ e2, unsigned long long* __restrict__ keys) {
  __shared__ float cs[CHUNK][DC];    // 64 KB
  __shared__ float ce2[CHUNK];
  const int k0 = blockIdx.x * CHUNK;
  const int t  = threadIdx.x;

  const float4* src = (const float4*)(embn + (size_t)k0 * DC);
  float4* dst = (float4*)&cs[0][0];
  for (int i = t; i < CHUNK * DC / 4; i += 256) dst[i] = src[i];
  for (int i = t; i < CHUNK; i += 256) ce2[i] = e2[k0 + i];

  const int ta = blockIdx.y * 512 + t;
  const int tb = ta + 256;
  float za[32], zb[32];
  #pragma unroll
  for (int i = 0; i < 8; ++i) {
    *(float4*)&za[i * 4] = *(const float4*)&zn[(size_t)ta * DC + i * 4];
    *(float4*)&zb[i * 4] = *(const float4*)&zn[(size_t)tb * DC + i * 4];
  }
  __syncthreads();

  float bda = 1e30f, bdb = 1e30f;
  int   bia = 0,     bib = 0;
  for (int cc = 0; cc < CHUNK; ++cc) {
    float p0 = 0.f, p1 = 0.f, p2 = 0.f, p3 = 0.f;
    float q0 = 0.f, q1 = 0.f, q2 = 0.f, q3 = 0.f;
    #pragma unroll
    for (int c = 0; c < DC; c += 4) {
      float4 cv = *(const float4*)&cs[cc][c];
      p0 = fmaf(za[c + 0], cv.x, p0);
      p1 = fmaf(za[c + 1], cv.y, p1);
      p2 = fmaf(za[c + 2], cv.z, p2);
      p3 = fmaf(za[c + 3], cv.w, p3);
      q0 = fmaf(zb[c + 0], cv.x, q0);
      q1 = fmaf(zb[c + 1], cv.y, q1);
      q2 = fmaf(zb[c + 2], cv.z, q2);
      q3 = fmaf(zb[c + 3], cv.w, q3);
    }
    float e  = ce2[cc];
    float da = fmaf(-2.f, (p0 + p1) + (p2 + p3), e);
    float db = fmaf(-2.f, (q0 + q1) + (q2 + q3), e);
    if (da < bda) { bda = da; bia = k0 + cc; }   // ascending scan: first-min kept
    if (db < bdb) { bdb = db; bib = k0 + cc; }
  }
  atomicMin(&keys[ta], packkey(bda, bia));
  atomicMin(&keys[tb], packkey(bdb, bib));
}

// ---------- K5: gather emb[idx], straight-through z_q, loss, idx-as-float ----------
__global__ __launch_bounds__(1024)
void kfinal(const unsigned long long* __restrict__ keys,
            const float* __restrict__ zn, const float* __restrict__ embn,
            float* __restrict__ zq, float* __restrict__ loss,
            float* __restrict__ oidx) {
  __shared__ float red[32];
  int t = blockIdx.x * blockDim.x + threadIdx.x;   // TOKENS*DC threads
  int tok = t >> 5, c = t & 31;
  unsigned long long key = keys[tok];
  int idx = (int)(unsigned int)(key & 0xFFFFFFFFull);
  float q = embn[(size_t)idx * DC + c];
  float z = zn[t];
  zq[t] = z + (q - z);
  float d = q - z;
  float ss = d * d;
  #pragma unroll
  for (int m = 16; m >= 1; m >>= 1) ss += __shfl_xor(ss, m, 32);
  if (c == 0) {
    red[threadIdx.x >> 5] = ss;
    oidx[tok] = (float)idx;
  }
  __syncthreads();
  if (threadIdx.x < 32) {
    float v = red[threadIdx.x];
    #pragma unroll
    for (int m = 16; m >= 1; m >>= 1) v += __shfl_xor(v, m, 32);
    if (threadIdx.x == 0)
      atomicAdd(loss, v * (1.0f / (float)(TOKENS * DC)));   // BETA = 1
  }
}

extern "C" void kernel_launch(void* const* d_in, const int* in_sizes, int n_in,
                              void* d_out, int out_size, void* d_ws, size_t ws_size,
                              hipStream_t stream) {
  const float* X   = (const float*)d_in[0];
  const float* W1  = (const float*)d_in[1];
  const float* B1  = (const float*)d_in[2];
  const float* W2  = (const float*)d_in[3];
  const float* B2  = (const float*)d_in[4];
  const float* CB  = (const float*)d_in[5];

  float* out  = (float*)d_out;
  float* zq   = out;                          // TOKENS*DC
  float* loss = out + (size_t)TOKENS * DC;    // 1
  float* oidx = loss + 1;                     // TOKENS (written as float)

  char* ws = (char*)d_ws;
  size_t off = 0;
  float* H    = (float*)(ws + off); off += (size_t)TOKENS * DENC * 4;   // 96 MB
  float* zn   = (float*)(ws + off); off += (size_t)TOKENS * DC * 4;     // 4 MB
  float* embn = (float*)(ws + off); off += (size_t)KC * DC * 4;         // 1 MB
  float* e2   = (float*)(ws + off); off += (size_t)KC * 4;              // 32 KB
  unsigned long long* keys = (unsigned long long*)(ws + off);           // 256 KB
  // W1 split arrays live in the zn region (zn is dead until kgemm2, which runs
  // after kgemm1 has fully consumed Wh/Wl): 2 * 768*768*2B = 2.25 MB < 4 MB.
  _Float16* Wh = (_Float16*)zn;
  _Float16* Wl = Wh + (size_t)DENC * DENC;

  hipMemsetAsync(loss, 0, sizeof(float), stream);
  hipMemsetAsync(keys, 0xFF, (size_t)TOKENS * 8, stream);   // key = +inf sentinel

  ksplitW<<<dim3(DENC / 256, DENC), 256, 0, stream>>>(W1, Wh, Wl);
  knorm_codes<<<(KC * DC) / 256, 256, 0, stream>>>(CB, embn, e2);
  kgemm1<<<(TOKENS / BM) * (DENC / BN), 256, 0, stream>>>(X, Wh, Wl, B1, H);
  kgemm2<<<(TOKENS * DC) / 256, 256, 0, stream>>>(H, W2, B2, zn);
  ksearch<<<dim3(KC / CHUNK, TOKENS / 512), 256, 0, stream>>>(zn, embn, e2, keys);
  kfinal<<<TOKENS * DC / 1024, 1024, 0, stream>>>(keys, zn, embn, zq, loss, oidx);
}

// Round 4
// 450.068 us; speedup vs baseline: 2.4565x; 1.4151x over previous
//
#include <hip/hip_runtime.h>
#include <hip/hip_bf16.h>
#include <cstdint>
#include <cstddef>

// VQKD forward: z = l2norm(tanh(X@W1+b1)@W2+b2); idx = argmin_k ||z-emb_k||^2 with
// emb = l2norm(codebook); z_q = emb[idx]; loss = mean((emb[idx]-z)^2).
// GEMM1 AND the code search run on f16 matrix cores with 2-way fp32 split
// (xh+xl)(wh+wl), 3 products: relative error ~3*2^-22 — argmin-safe (validated r3).

namespace {
constexpr int TOKENS = 8 * 4096;   // 32768
constexpr int DENC   = 768;
constexpr int DC     = 32;
constexpr int KC     = 8192;
constexpr int BM = 128, BN = 128, BK = 64;   // MFMA tile for GEMM1
constexpr float WSCALE = 1024.0f;  // keeps w_lo out of fp16 subnormals
constexpr float SSCALE = 512.0f;   // 2^9: z/emb split scale (exact, ordering-preserving)
constexpr int SCH = 256;           // codes per LDS chunk in ksearch
}

typedef _Float16 f16x8 __attribute__((ext_vector_type(8)));
typedef float    f32x4 __attribute__((ext_vector_type(4)));

__device__ inline void split2(float v, _Float16& h, _Float16& l) {
  h = (_Float16)v;
  l = (_Float16)(v - (float)h);
}

// ---------- K0: split W1 (scaled) into fp16 hi/lo, TRANSPOSED to [N][K] ----------
__global__ void ksplitW(const float* __restrict__ W1,
                        _Float16* __restrict__ Wh, _Float16* __restrict__ Wl) {
  int n = blockIdx.y;                               // 768
  int k = blockIdx.x * 256 + threadIdx.x;           // 768
  float w = W1[(size_t)k * DENC + n] * WSCALE;      // strided read (L2-resident)
  _Float16 h, l; split2(w, h, l);
  Wh[(size_t)n * DENC + k] = h;                     // coalesced write
  Wl[(size_t)n * DENC + k] = l;
}

// ---------- K1: normalize codebook; emit embn (fp32), split Eh/El (x512), se2 ----------
__global__ void knorm_codes(const float* __restrict__ cb,
                            float* __restrict__ embn, float* __restrict__ se2,
                            _Float16* __restrict__ Eh, _Float16* __restrict__ El) {
  int t = blockIdx.x * blockDim.x + threadIdx.x;      // KC*DC threads
  int k = t >> 5, c = t & 31;
  float v = cb[(size_t)k * DC + c];
  float ss = v * v;
  #pragma unroll
  for (int m = 16; m >= 1; m >>= 1) ss += __shfl_xor(ss, m, 32);
  float nrm = fmaxf(sqrtf(ss), 1e-12f);
  float vn = v / nrm;
  embn[(size_t)k * DC + c] = vn;
  _Float16 h, l; split2(vn * SSCALE, h, l);
  Eh[(size_t)k * DC + c] = h;
  El[(size_t)k * DC + c] = l;
  float s2 = vn * vn;
  #pragma unroll
  for (int m = 16; m >= 1; m >>= 1) s2 += __shfl_xor(s2, m, 32);
  if (c == 0) se2[k] = s2 * (SSCALE * SSCALE);   // 2^18 * e2: exact scaling
}

// ---------- K2: H = tanh(X @ W1 + b1) via MFMA f16 split-2 (3 passes) ----------
__global__ __launch_bounds__(256, 2)
void kgemm1(const float* __restrict__ X,
            const _Float16* __restrict__ Wh, const _Float16* __restrict__ Wl,
            const float* __restrict__ bias1, float* __restrict__ H) {
  __shared__ __align__(16) _Float16 Ah[8][BM][8], Al[8][BM][8];  // 16 KB each
  __shared__ __align__(16) _Float16 Bh[8][BN][8], Bl[8][BN][8];  // total 64 KB

  const int bid = blockIdx.x;
  const int xcd = bid & 7;
  const int w   = bid >> 3;            // 0..191
  const int n_t = w % 6;
  const int m_t = xcd * 32 + w / 6;
  const int m0 = m_t * BM, n0 = n_t * BN;

  const int t    = threadIdx.x;
  const int lane = t & 63;
  const int wv   = t >> 6;
  const int wm   = wv >> 1, wn = wv & 1;
  const int lrow = lane & 15;
  const int lgrp = lane >> 4;

  const int arow = t & 127;
  const int ag   = t >> 7;
  const int bcol = t & 127;
  const int barr = t >> 7;

  const float*    xp = X  + (size_t)(m0 + arow) * DENC + ag * 32;
  const _Float16* wp = (barr ? Wl : Wh) + (size_t)(n0 + bcol) * DENC;

  f32x4 acc[4][4];
  #pragma unroll
  for (int i = 0; i < 4; ++i)
    #pragma unroll
    for (int j = 0; j < 4; ++j) acc[i][j] = (f32x4)0.0f;

  float4 pa[8];
  f16x8  pb[8];

  #pragma unroll
  for (int j = 0; j < 4; ++j) {
    pa[2*j]   = *(const float4*)&xp[j * 8];
    pa[2*j+1] = *(const float4*)&xp[j * 8 + 4];
  }
  #pragma unroll
  for (int j = 0; j < 8; ++j) pb[j] = *(const f16x8*)&wp[j * 8];

  for (int step = 0; step < DENC / BK; ++step) {
    __syncthreads();
    #pragma unroll
    for (int j = 0; j < 4; ++j) {
      float v[8] = { pa[2*j].x, pa[2*j].y, pa[2*j].z, pa[2*j].w,
                     pa[2*j+1].x, pa[2*j+1].y, pa[2*j+1].z, pa[2*j+1].w };
      f16x8 hh, ll;
      #pragma unroll
      for (int e = 0; e < 8; ++e) { _Float16 h, l; split2(v[e], h, l); hh[e] = h; ll[e] = l; }
      *(f16x8*)&Ah[ag * 4 + j][arow][0] = hh;
      *(f16x8*)&Al[ag * 4 + j][arow][0] = ll;
    }
    {
      _Float16 (*Bd)[BN][8] = barr ? Bl : Bh;
      #pragma unroll
      for (int j = 0; j < 8; ++j) *(f16x8*)&Bd[j][bcol][0] = pb[j];
    }
    __syncthreads();

    if (step < DENC / BK - 1) {
      xp += BK; wp += BK;
      #pragma unroll
      for (int j = 0; j < 4; ++j) {
        pa[2*j]   = *(const float4*)&xp[j * 8];
        pa[2*j+1] = *(const float4*)&xp[j * 8 + 4];
      }
      #pragma unroll
      for (int j = 0; j < 8; ++j) pb[j] = *(const f16x8*)&wp[j * 8];
    }

    #pragma unroll
    for (int s = 0; s < 2; ++s) {
      const int ko = s * 4 + lgrp;
      f16x8 nbh[4], nbl[4];
      #pragma unroll
      for (int nf = 0; nf < 4; ++nf) {
        const int col = wn * 64 + nf * 16 + lrow;
        nbh[nf] = *(const f16x8*)&Bh[ko][col][0];
        nbl[nf] = *(const f16x8*)&Bl[ko][col][0];
      }
      #pragma unroll
      for (int mf = 0; mf < 4; ++mf) {
        const int row = wm * 64 + mf * 16 + lrow;
        f16x8 mah = *(const f16x8*)&Ah[ko][row][0];
        f16x8 mal = *(const f16x8*)&Al[ko][row][0];
        #pragma unroll
        for (int nf = 0; nf < 4; ++nf) {
          acc[mf][nf] = __builtin_amdgcn_mfma_f32_16x16x32_f16(mah, nbh[nf], acc[mf][nf], 0, 0, 0);
          acc[mf][nf] = __builtin_amdgcn_mfma_f32_16x16x32_f16(mah, nbl[nf], acc[mf][nf], 0, 0, 0);
          acc[mf][nf] = __builtin_amdgcn_mfma_f32_16x16x32_f16(mal, nbh[nf], acc[mf][nf], 0, 0, 0);
        }
      }
    }
  }

  #pragma unroll
  for (int nf = 0; nf < 4; ++nf) {
    const int col = n0 + wn * 64 + nf * 16 + lrow;
    const float b = bias1[col];
    #pragma unroll
    for (int mf = 0; mf < 4; ++mf) {
      #pragma unroll
      for (int r = 0; r < 4; ++r) {
        const int row = m0 + wm * 64 + mf * 16 + lgrp * 4 + r;
        H[(size_t)row * DENC + col] = tanhf(acc[mf][nf][r] * (1.0f / WSCALE) + b);
      }
    }
  }
}

// ---------- K3: z = H @ W2 + b2, then l2-normalize rows -> zn ----------
__global__ void kgemm2(const float* __restrict__ H, const float* __restrict__ W2,
                       const float* __restrict__ b2, float* __restrict__ zn) {
  int t = blockIdx.x * blockDim.x + threadIdx.x;   // TOKENS*DC threads
  int tok = t >> 5, c = t & 31;
  const float* h = H + (size_t)tok * DENC;
  float a0 = 0.f, a1 = 0.f, a2 = 0.f, a3 = 0.f;
  for (int k = 0; k < DENC; k += 4) {
    float4 hv = *(const float4*)&h[k];
    a0 = fmaf(hv.x, W2[(size_t)(k + 0) * DC + c], a0);
    a1 = fmaf(hv.y, W2[(size_t)(k + 1) * DC + c], a1);
    a2 = fmaf(hv.z, W2[(size_t)(k + 2) * DC + c], a2);
    a3 = fmaf(hv.w, W2[(size_t)(k + 3) * DC + c], a3);
  }
  float z = ((a0 + a1) + (a2 + a3)) + b2[c];
  float ss = z * z;
  #pragma unroll
  for (int m = 16; m >= 1; m >>= 1) ss += __shfl_xor(ss, m, 32);
  float nrm = fmaxf(sqrtf(ss), 1e-12f);
  zn[t] = z / nrm;
}

__device__ inline unsigned long long packkey(float d, int idx) {
  unsigned int u = __float_as_uint(d);
  u = (u & 0x80000000u) ? ~u : (u | 0x80000000u);   // monotone float->uint
  return ((unsigned long long)u << 32) | (unsigned int)idx;
}

// ---------- K4: nearest code via MFMA split-2 GEMM + in-register argmin ----------
// Wave = 64 tokens (4 A-frags in regs), block = 256 tokens; grid.y splits codes
// 8-ways (1024 codes/block, LDS-staged in 256-code chunks, 33 KB -> 4 blocks/CU).
// d' = 2^18*e2 - 2*s' (s' = scaled dot): exact-scaled, ordering == unscaled.
__global__ __launch_bounds__(256, 3)
void ksearch(const float* __restrict__ zn, const _Float16* __restrict__ Eh,
             const _Float16* __restrict__ El, const float* __restrict__ se2,
             unsigned long long* __restrict__ keys) {
  __shared__ __align__(16) _Float16 Bh[4][SCH][8], Bl[4][SCH][8];  // 32 KB
  __shared__ float ce2[SCH];                                        // 1 KB
  const int t = threadIdx.x, lane = t & 63, wv = t >> 6;
  const int tb  = blockIdx.x * 256 + wv * 64;
  const int cb0 = blockIdx.y * 1024;
  const int lr = lane & 15, ko = lane >> 4;

  // A-frags: 4 m-frags of 16 tokens; lane holds row=lane&15, k-octet=lane>>4.
  f16x8 azh[4], azl[4];
  #pragma unroll
  for (int m = 0; m < 4; ++m) {
    const float* zp = zn + (size_t)(tb + m * 16 + lr) * DC + ko * 8;
    float4 u = *(const float4*)zp, v = *(const float4*)(zp + 4);
    float vals[8] = {u.x, u.y, u.z, u.w, v.x, v.y, v.z, v.w};
    f16x8 hh, ll;
    #pragma unroll
    for (int e = 0; e < 8; ++e) {
      float sv = vals[e] * SSCALE;
      _Float16 h, l; split2(sv, h, l);
      hh[e] = h; ll[e] = l;
    }
    azh[m] = hh; azl[m] = ll;
  }

  float best[4][4]; int bi[4][4];
  #pragma unroll
  for (int m = 0; m < 4; ++m)
    #pragma unroll
    for (int r = 0; r < 4; ++r) { best[m][r] = 3.4e38f; bi[m][r] = 0; }

  f16x8 pb[8]; float pe2;

  for (int ch = 0; ch < 4; ++ch) {
    const int cb = cb0 + ch * SCH;
    // load chunk to regs (t == code within chunk; SCH == blockDim)
    #pragma unroll
    for (int it = 0; it < 8; ++it) {
      const _Float16* src = (it < 4) ? Eh : El;
      pb[it] = *(const f16x8*)&src[(size_t)(cb + t) * DC + (it & 3) * 8];
    }
    pe2 = se2[cb + t];
    __syncthreads();   // previous chunk's LDS reads complete
    #pragma unroll
    for (int it = 0; it < 8; ++it) {
      _Float16 (*B)[SCH][8] = (it < 4) ? Bh : Bl;
      *(f16x8*)&B[it & 3][t][0] = pb[it];
    }
    ce2[t] = pe2;
    __syncthreads();

    #pragma unroll 4
    for (int f = 0; f < SCH / 16; ++f) {
      f16x8 bh = *(const f16x8*)&Bh[ko][f * 16 + lr][0];
      f16x8 bl = *(const f16x8*)&Bl[ko][f * 16 + lr][0];
      float e2v = ce2[f * 16 + lr];
      int  code = cb + f * 16 + lr;
      #pragma unroll
      for (int m = 0; m < 4; ++m) {
        f32x4 a = (f32x4)0.0f;
        a = __builtin_amdgcn_mfma_f32_16x16x32_f16(azh[m], bh, a, 0, 0, 0);
        a = __builtin_amdgcn_mfma_f32_16x16x32_f16(azh[m], bl, a, 0, 0, 0);
        a = __builtin_amdgcn_mfma_f32_16x16x32_f16(azl[m], bh, a, 0, 0, 0);
        #pragma unroll
        for (int r = 0; r < 4; ++r) {
          float d = fmaf(-2.0f, a[r], e2v);
          bool c = d < best[m][r];            // strict <: first (lowest) code wins ties
          best[m][r] = c ? d : best[m][r];
          bi[m][r]   = c ? code : bi[m][r];
        }
      }
    }
  }

  // reduce across the 16 code-lanes (C layout: row=(lane>>4)*4+r, col=lane&15)
  #pragma unroll
  for (int m = 0; m < 4; ++m)
    #pragma unroll
    for (int r = 0; r < 4; ++r) {
      float bd = best[m][r]; int ix = bi[m][r];
      #pragma unroll
      for (int s = 1; s < 16; s <<= 1) {
        float od = __shfl_xor(bd, s);
        int   oi = __shfl_xor(ix, s);
        if (od < bd || (od == bd && oi < ix)) { bd = od; ix = oi; }
      }
      if ((lane & 15) == 0) {
        int token = tb + m * 16 + (lane >> 4) * 4 + r;
        atomicMin(&keys[token], packkey(bd, ix));
      }
    }
}

// ---------- K5: gather emb[idx], straight-through z_q, loss, idx-as-float ----------
__global__ __launch_bounds__(1024)
void kfinal(const unsigned long long* __restrict__ keys,
            const float* __restrict__ zn, const float* __restrict__ embn,
            float* __restrict__ zq, float* __restrict__ loss,
            float* __restrict__ oidx) {
  __shared__ float red[32];
  int t = blockIdx.x * blockDim.x + threadIdx.x;   // TOKENS*DC threads
  int tok = t >> 5, c = t & 31;
  unsigned long long key = keys[tok];
  int idx = (int)(unsigned int)(key & 0xFFFFFFFFull);
  float q = embn[(size_t)idx * DC + c];
  float z = zn[t];
  zq[t] = z + (q - z);
  float d = q - z;
  float ss = d * d;
  #pragma unroll
  for (int m = 16; m >= 1; m >>= 1) ss += __shfl_xor(ss, m, 32);
  if (c == 0) {
    red[threadIdx.x >> 5] = ss;
    oidx[tok] = (float)idx;
  }
  __syncthreads();
  if (threadIdx.x < 32) {
    float v = red[threadIdx.x];
    #pragma unroll
    for (int m = 16; m >= 1; m >>= 1) v += __shfl_xor(v, m, 32);
    if (threadIdx.x == 0)
      atomicAdd(loss, v * (1.0f / (float)(TOKENS * DC)));   // BETA = 1
  }
}

extern "C" void kernel_launch(void* const* d_in, const int* in_sizes, int n_in,
                              void* d_out, int out_size, void* d_ws, size_t ws_size,
                              hipStream_t stream) {
  const float* X   = (const float*)d_in[0];
  const float* W1  = (const float*)d_in[1];
  const float* B1  = (const float*)d_in[2];
  const float* W2  = (const float*)d_in[3];
  const float* B2  = (const float*)d_in[4];
  const float* CB  = (const float*)d_in[5];

  float* out  = (float*)d_out;
  float* zq   = out;                          // TOKENS*DC
  float* loss = out + (size_t)TOKENS * DC;    // 1
  float* oidx = loss + 1;                     // TOKENS (written as float)

  char* ws = (char*)d_ws;
  size_t off = 0;
  float* H    = (float*)(ws + off); off += (size_t)TOKENS * DENC * 4;   // 96 MB
  float* zn   = (float*)(ws + off); off += (size_t)TOKENS * DC * 4;     // 4 MB
  float* embn = (float*)(ws + off); off += (size_t)KC * DC * 4;         // 1 MB
  float* se2  = (float*)(ws + off); off += (size_t)KC * 4;              // 32 KB
  _Float16* Eh = (_Float16*)(ws + off); off += (size_t)KC * DC * 2;     // 512 KB
  _Float16* El = (_Float16*)(ws + off); off += (size_t)KC * DC * 2;     // 512 KB
  unsigned long long* keys = (unsigned long long*)(ws + off);           // 256 KB
  // W1 split arrays alias the zn region (zn written only by kgemm2, after
  // kgemm1 consumed Wh/Wl): 2 * 768*768*2B = 2.25 MB < 4 MB.
  _Float16* Wh = (_Float16*)zn;
  _Float16* Wl = Wh + (size_t)DENC * DENC;

  hipMemsetAsync(loss, 0, sizeof(float), stream);
  hipMemsetAsync(keys, 0xFF, (size_t)TOKENS * 8, stream);   // +inf sentinel

  ksplitW<<<dim3(DENC / 256, DENC), 256, 0, stream>>>(W1, Wh, Wl);
  knorm_codes<<<(KC * DC) / 256, 256, 0, stream>>>(CB, embn, se2, Eh, El);
  kgemm1<<<(TOKENS / BM) * (DENC / BN), 256, 0, stream>>>(X, Wh, Wl, B1, H);
  kgemm2<<<(TOKENS * DC) / 256, 256, 0, stream>>>(H, W2, B2, zn);
  ksearch<<<dim3(TOKENS / 256, KC / 1024), 256, 0, stream>>>(zn, Eh, El, se2, keys);
  kfinal<<<TOKENS * DC / 1024, 1024, 0, stream>>>(keys, zn, embn, zq, loss, oidx);
}

// Round 5
// 368.505 us; speedup vs baseline: 3.0003x; 1.2213x over previous
//
#include <hip/hip_runtime.h>
#include <hip/hip_bf16.h>
#include <cstdint>
#include <cstddef>

// VQKD forward: z = l2norm(tanh(X@W1+b1)@W2+b2); idx = argmin_k ||z-emb_k||^2 with
// emb = l2norm(codebook); z_q = emb[idx]; loss = mean((emb[idx]-z)^2).
// All GEMM-shaped work on f16 matrix cores with 2-way fp32 split (3 products):
// rel error ~3*2^-22 — argmin-safe (validated r3/r4, absmax 2.4e-4 both rounds).

namespace {
constexpr int TOKENS = 8 * 4096;   // 32768
constexpr int DENC   = 768;
constexpr int DC     = 32;
constexpr int KC     = 8192;
constexpr int BM = 128, BN = 128, BK = 64;   // kgemm1 tile
constexpr float WSCALE = 1024.0f;  // weight split scale (keeps lo out of subnormals)
constexpr float HSCALE = 512.0f;   // H split scale (tanh out in [-1,1] -> lo ~0.06 normal)
constexpr float SSCALE = 512.0f;   // z/emb split scale for ksearch (2^9: exact)
constexpr int SCH = 256;           // codes per LDS chunk in ksearch
}

typedef _Float16 f16x8 __attribute__((ext_vector_type(8)));
typedef float    f32x4 __attribute__((ext_vector_type(4)));

__device__ inline void split2(float v, _Float16& h, _Float16& l) {
  h = (_Float16)v;
  l = (_Float16)(v - (float)h);
}

__device__ inline void gload_lds16(const void* g, void* l) {
  __builtin_amdgcn_global_load_lds(
      (const __attribute__((address_space(1))) void*)g,
      (__attribute__((address_space(3))) void*)l, 16, 0, 0);
}

// ---------- K0a: split W1 (x1024) into fp16 hi/lo, TRANSPOSED to [N][K] ----------
__global__ void ksplitW(const float* __restrict__ W1,
                        _Float16* __restrict__ Wh, _Float16* __restrict__ Wl) {
  int n = blockIdx.y;
  int k = blockIdx.x * 256 + threadIdx.x;
  float w = W1[(size_t)k * DENC + n] * WSCALE;
  _Float16 h, l; split2(w, h, l);
  Wh[(size_t)n * DENC + k] = h;
  Wl[(size_t)n * DENC + k] = l;
}

// ---------- K0b: split W2 (x1024) into fp16 hi/lo, TRANSPOSED to [32][768] ----------
__global__ void ksplitW2(const float* __restrict__ W2,
                         _Float16* __restrict__ W2h, _Float16* __restrict__ W2l) {
  int i = blockIdx.x * 256 + threadIdx.x;    // 768*32
  int k = i >> 5, c = i & 31;
  float w = W2[(size_t)k * DC + c] * WSCALE;
  _Float16 h, l; split2(w, h, l);
  W2h[(size_t)c * DENC + k] = h;
  W2l[(size_t)c * DENC + k] = l;
}

// ---------- K1: normalize codebook; emit embn (fp32), split Eh/El (x512), se2 ----------
__global__ void knorm_codes(const float* __restrict__ cb,
                            float* __restrict__ embn, float* __restrict__ se2,
                            _Float16* __restrict__ Eh, _Float16* __restrict__ El) {
  int t = blockIdx.x * blockDim.x + threadIdx.x;
  int k = t >> 5, c = t & 31;
  float v = cb[(size_t)k * DC + c];
  float ss = v * v;
  #pragma unroll
  for (int m = 16; m >= 1; m >>= 1) ss += __shfl_xor(ss, m, 32);
  float nrm = fmaxf(sqrtf(ss), 1e-12f);
  float vn = v / nrm;
  embn[(size_t)k * DC + c] = vn;
  _Float16 h, l; split2(vn * SSCALE, h, l);
  Eh[(size_t)k * DC + c] = h;
  El[(size_t)k * DC + c] = l;
  float s2 = vn * vn;
  #pragma unroll
  for (int m = 16; m >= 1; m >>= 1) s2 += __shfl_xor(s2, m, 32);
  if (c == 0) se2[k] = s2 * (SSCALE * SSCALE);
}

// ---------- K2: Hh/Hl = split(512*tanh(X@W1+b1)) via MFMA split-2 ----------
// A: X fp32 global -> regs -> split -> register fragments (no LDS; rows shared
// only 2-way).  B: pre-split W1h/l staged via global_load_lds into double-
// buffered LDS, ONE barrier per K-step (stage s+1 issued before compute s).
// LDS pipe per wave-step: 16 frag reads (was 32 reads + 16 writes).
__global__ __launch_bounds__(256, 2)
void kgemm1(const float* __restrict__ X,
            const _Float16* __restrict__ Wh, const _Float16* __restrict__ Wl,
            const float* __restrict__ bias1,
            _Float16* __restrict__ Hh, _Float16* __restrict__ Hl) {
  __shared__ __align__(16) _Float16 Bs[2][2][8][BN][8];   // [buf][h/l][ko][col][8] = 64 KB

  // XCD-aware bijective swizzle (1536 blocks = 8 XCD * 192; 192 = 32 Mt * 6 Nt)
  const int bid = blockIdx.x;
  const int xcd = bid & 7;
  const int w   = bid >> 3;
  const int n_t = w % 6;
  const int m_t = xcd * 32 + w / 6;
  const int m0 = m_t * BM, n0 = n_t * BN;

  const int t    = threadIdx.x;
  const int lane = t & 63;
  const int wv   = t >> 6;
  const int wm   = wv >> 1, wn = wv & 1;
  const int lrow = lane & 15;
  const int lgrp = lane >> 4;

  // B staging role: wave wv handles array arr=wv>>1 (0=h,1=l), col-half ch=wv&1
  const int sarr = wv >> 1, sch = wv & 1;
  const _Float16* wlane = (sarr ? Wl : Wh) + (size_t)(n0 + sch * 64 + lane) * DENC;

  // A per-lane row base pointers (element index includes lgrp*8)
  const float* xb[4];
  #pragma unroll
  for (int mf = 0; mf < 4; ++mf)
    xb[mf] = X + (size_t)(m0 + wm * 64 + mf * 16 + lrow) * DENC + lgrp * 8;

  f32x4 acc[4][4];
  #pragma unroll
  for (int i = 0; i < 4; ++i)
    #pragma unroll
    for (int j = 0; j < 4; ++j) acc[i][j] = (f32x4)0.0f;

  float4 pax[16];

  // prologue: stage step 0 into buf 0, load A step 0
  #pragma unroll
  for (int ko = 0; ko < 8; ++ko)
    gload_lds16(wlane + ko * 8, &Bs[0][sarr][ko][sch * 64][0]);
  #pragma unroll
  for (int sl = 0; sl < 2; ++sl)
    #pragma unroll
    for (int mf = 0; mf < 4; ++mf) {
      const float* p = xb[mf] + sl * 32;
      pax[(sl * 4 + mf) * 2]     = *(const float4*)p;
      pax[(sl * 4 + mf) * 2 + 1] = *(const float4*)(p + 4);
    }

  for (int s = 0; s < DENC / BK; ++s) {
    const int cur = s & 1;
    __syncthreads();   // implicit vmcnt(0) drain: Bs[cur] ready, pax ready

    // split current A into register fragments
    f16x8 ah[2][4], al[2][4];
    #pragma unroll
    for (int sl = 0; sl < 2; ++sl)
      #pragma unroll
      for (int mf = 0; mf < 4; ++mf) {
        float4 u = pax[(sl * 4 + mf) * 2], v = pax[(sl * 4 + mf) * 2 + 1];
        float vals[8] = {u.x, u.y, u.z, u.w, v.x, v.y, v.z, v.w};
        f16x8 hh, ll;
        #pragma unroll
        for (int e = 0; e < 8; ++e) { _Float16 h, l; split2(vals[e], h, l); hh[e] = h; ll[e] = l; }
        ah[sl][mf] = hh; al[sl][mf] = ll;
      }

    // issue next step's staging (in flight across the whole MFMA phase)
    if (s < DENC / BK - 1) {
      const _Float16* wsrc = wlane + (s + 1) * BK;
      #pragma unroll
      for (int ko = 0; ko < 8; ++ko)
        gload_lds16(wsrc + ko * 8, &Bs[cur ^ 1][sarr][ko][sch * 64][0]);
      #pragma unroll
      for (int sl = 0; sl < 2; ++sl)
        #pragma unroll
        for (int mf = 0; mf < 4; ++mf) {
          const float* p = xb[mf] + (s + 1) * BK + sl * 32;
          pax[(sl * 4 + mf) * 2]     = *(const float4*)p;
          pax[(sl * 4 + mf) * 2 + 1] = *(const float4*)(p + 4);
        }
    }

    // MFMA phase
    #pragma unroll
    for (int sl = 0; sl < 2; ++sl) {
      const int ko = sl * 4 + lgrp;
      f16x8 nbh[4], nbl[4];
      #pragma unroll
      for (int nf = 0; nf < 4; ++nf) {
        const int col = wn * 64 + nf * 16 + lrow;
        nbh[nf] = *(const f16x8*)&Bs[cur][0][ko][col][0];
        nbl[nf] = *(const f16x8*)&Bs[cur][1][ko][col][0];
      }
      #pragma unroll
      for (int mf = 0; mf < 4; ++mf) {
        #pragma unroll
        for (int nf = 0; nf < 4; ++nf) {
          acc[mf][nf] = __builtin_amdgcn_mfma_f32_16x16x32_f16(ah[sl][mf], nbh[nf], acc[mf][nf], 0, 0, 0);
          acc[mf][nf] = __builtin_amdgcn_mfma_f32_16x16x32_f16(ah[sl][mf], nbl[nf], acc[mf][nf], 0, 0, 0);
          acc[mf][nf] = __builtin_amdgcn_mfma_f32_16x16x32_f16(al[sl][mf], nbh[nf], acc[mf][nf], 0, 0, 0);
        }
      }
    }
  }

  // epilogue: un-scale, bias, tanh, split x512, store both fp16 planes
  #pragma unroll
  for (int nf = 0; nf < 4; ++nf) {
    const int col = n0 + wn * 64 + nf * 16 + lrow;
    const float b = bias1[col];
    #pragma unroll
    for (int mf = 0; mf < 4; ++mf) {
      #pragma unroll
      for (int r = 0; r < 4; ++r) {
        const int row = m0 + wm * 64 + mf * 16 + lgrp * 4 + r;
        float tv = tanhf(acc[mf][nf][r] * (1.0f / WSCALE) + b) * HSCALE;
        _Float16 h, l; split2(tv, h, l);
        Hh[(size_t)row * DENC + col] = h;
        Hl[(size_t)row * DENC + col] = l;
      }
    }
  }
}

// ---------- K3: zn = l2norm(H @ W2 + b2) via pure-register MFMA split-2 ----------
// No LDS, no barriers. Wave = 32 tokens (2 m-frags x 2 n-frags), block = 2 waves.
// A = Hh/Hl (fp16 planes), B = transposed pre-split W2 (L1/L2-resident).
__global__ __launch_bounds__(128, 4)
void kgemm2(const _Float16* __restrict__ Hh, const _Float16* __restrict__ Hl,
            const _Float16* __restrict__ W2h, const _Float16* __restrict__ W2l,
            const float* __restrict__ b2, float* __restrict__ zn) {
  const int t = threadIdx.x, lane = t & 63, wv = t >> 6;
  const int lrow = lane & 15, lgrp = lane >> 4;
  const int tb = blockIdx.x * 64 + wv * 32;

  const _Float16* ah_p[2]; const _Float16* al_p[2];
  #pragma unroll
  for (int mf = 0; mf < 2; ++mf) {
    size_t roff = (size_t)(tb + mf * 16 + lrow) * DENC + lgrp * 8;
    ah_p[mf] = Hh + roff; al_p[mf] = Hl + roff;
  }
  const _Float16* bh_p[2]; const _Float16* bl_p[2];
  #pragma unroll
  for (int nf = 0; nf < 2; ++nf) {
    size_t coff = (size_t)(nf * 16 + lrow) * DENC + lgrp * 8;
    bh_p[nf] = W2h + coff; bl_p[nf] = W2l + coff;
  }

  f32x4 acc[2][2];
  #pragma unroll
  for (int i = 0; i < 2; ++i)
    #pragma unroll
    for (int j = 0; j < 2; ++j) acc[i][j] = (f32x4)0.0f;

  for (int s = 0; s < DENC / 64; ++s) {
    #pragma unroll
    for (int sl = 0; sl < 2; ++sl) {
      const int koff = s * 64 + sl * 32;
      f16x8 a_h[2], a_l[2], b_h[2], b_l[2];
      #pragma unroll
      for (int mf = 0; mf < 2; ++mf) {
        a_h[mf] = *(const f16x8*)(ah_p[mf] + koff);
        a_l[mf] = *(const f16x8*)(al_p[mf] + koff);
      }
      #pragma unroll
      for (int nf = 0; nf < 2; ++nf) {
        b_h[nf] = *(const f16x8*)(bh_p[nf] + koff);
        b_l[nf] = *(const f16x8*)(bl_p[nf] + koff);
      }
      #pragma unroll
      for (int mf = 0; mf < 2; ++mf)
        #pragma unroll
        for (int nf = 0; nf < 2; ++nf) {
          acc[mf][nf] = __builtin_amdgcn_mfma_f32_16x16x32_f16(a_h[mf], b_h[nf], acc[mf][nf], 0, 0, 0);
          acc[mf][nf] = __builtin_amdgcn_mfma_f32_16x16x32_f16(a_h[mf], b_l[nf], acc[mf][nf], 0, 0, 0);
          acc[mf][nf] = __builtin_amdgcn_mfma_f32_16x16x32_f16(a_l[mf], b_h[nf], acc[mf][nf], 0, 0, 0);
        }
    }
  }

  // epilogue: z = acc/2^19 + b2; row-wise l2norm over 32 cols; store zn
  const float inv = 1.0f / (HSCALE * WSCALE);
  float bv[2];
  #pragma unroll
  for (int nf = 0; nf < 2; ++nf) bv[nf] = b2[nf * 16 + lrow];
  #pragma unroll
  for (int mf = 0; mf < 2; ++mf) {
    float z[2][4], ss[4];
    #pragma unroll
    for (int r = 0; r < 4; ++r) {
      #pragma unroll
      for (int nf = 0; nf < 2; ++nf) z[nf][r] = acc[mf][nf][r] * inv + bv[nf];
      float s2 = z[0][r] * z[0][r] + z[1][r] * z[1][r];
      #pragma unroll
      for (int m = 8; m >= 1; m >>= 1) s2 += __shfl_xor(s2, m, 16);
      ss[r] = s2;
    }
    #pragma unroll
    for (int r = 0; r < 4; ++r) {
      const int row = tb + mf * 16 + lgrp * 4 + r;
      float nrm = fmaxf(sqrtf(ss[r]), 1e-12f);
      #pragma unroll
      for (int nf = 0; nf < 2; ++nf)
        zn[(size_t)row * DC + nf * 16 + lrow] = z[nf][r] / nrm;
    }
  }
}

__device__ inline unsigned long long packkey(float d, int idx) {
  unsigned int u = __float_as_uint(d);
  u = (u & 0x80000000u) ? ~u : (u | 0x80000000u);
  return ((unsigned long long)u << 32) | (unsigned int)idx;
}

// ---------- K4: nearest code via MFMA split-2 GEMM + in-register argmin ----------
__global__ __launch_bounds__(256, 3)
void ksearch(const float* __restrict__ zn, const _Float16* __restrict__ Eh,
             const _Float16* __restrict__ El, const float* __restrict__ se2,
             unsigned long long* __restrict__ keys) {
  __shared__ __align__(16) _Float16 Bh[4][SCH][8], Bl[4][SCH][8];  // 32 KB
  __shared__ float ce2[SCH];
  const int t = threadIdx.x, lane = t & 63, wv = t >> 6;
  const int tb  = blockIdx.x * 256 + wv * 64;
  const int cb0 = blockIdx.y * 1024;
  const int lr = lane & 15, ko = lane >> 4;

  f16x8 azh[4], azl[4];
  #pragma unroll
  for (int m = 0; m < 4; ++m) {
    const float* zp = zn + (size_t)(tb + m * 16 + lr) * DC + ko * 8;
    float4 u = *(const float4*)zp, v = *(const float4*)(zp + 4);
    float vals[8] = {u.x, u.y, u.z, u.w, v.x, v.y, v.z, v.w};
    f16x8 hh, ll;
    #pragma unroll
    for (int e = 0; e < 8; ++e) {
      float sv = vals[e] * SSCALE;
      _Float16 h, l; split2(sv, h, l);
      hh[e] = h; ll[e] = l;
    }
    azh[m] = hh; azl[m] = ll;
  }

  float best[4][4]; int bi[4][4];
  #pragma unroll
  for (int m = 0; m < 4; ++m)
    #pragma unroll
    for (int r = 0; r < 4; ++r) { best[m][r] = 3.4e38f; bi[m][r] = 0; }

  f16x8 pb[8]; float pe2;

  for (int ch = 0; ch < 4; ++ch) {
    const int cb = cb0 + ch * SCH;
    #pragma unroll
    for (int it = 0; it < 8; ++it) {
      const _Float16* src = (it < 4) ? Eh : El;
      pb[it] = *(const f16x8*)&src[(size_t)(cb + t) * DC + (it & 3) * 8];
    }
    pe2 = se2[cb + t];
    __syncthreads();
    #pragma unroll
    for (int it = 0; it < 8; ++it) {
      _Float16 (*B)[SCH][8] = (it < 4) ? Bh : Bl;
      *(f16x8*)&B[it & 3][t][0] = pb[it];
    }
    ce2[t] = pe2;
    __syncthreads();

    #pragma unroll 4
    for (int f = 0; f < SCH / 16; ++f) {
      f16x8 bh = *(const f16x8*)&Bh[ko][f * 16 + lr][0];
      f16x8 bl = *(const f16x8*)&Bl[ko][f * 16 + lr][0];
      float e2v = ce2[f * 16 + lr];
      int  code = cb + f * 16 + lr;
      #pragma unroll
      for (int m = 0; m < 4; ++m) {
        f32x4 a = (f32x4)0.0f;
        a = __builtin_amdgcn_mfma_f32_16x16x32_f16(azh[m], bh, a, 0, 0, 0);
        a = __builtin_amdgcn_mfma_f32_16x16x32_f16(azh[m], bl, a, 0, 0, 0);
        a = __builtin_amdgcn_mfma_f32_16x16x32_f16(azl[m], bh, a, 0, 0, 0);
        #pragma unroll
        for (int r = 0; r < 4; ++r) {
          float d = fmaf(-2.0f, a[r], e2v);
          bool c = d < best[m][r];
          best[m][r] = c ? d : best[m][r];
          bi[m][r]   = c ? code : bi[m][r];
        }
      }
    }
  }

  #pragma unroll
  for (int m = 0; m < 4; ++m)
    #pragma unroll
    for (int r = 0; r < 4; ++r) {
      float bd = best[m][r]; int ix = bi[m][r];
      #pragma unroll
      for (int s = 1; s < 16; s <<= 1) {
        float od = __shfl_xor(bd, s);
        int   oi = __shfl_xor(ix, s);
        if (od < bd || (od == bd && oi < ix)) { bd = od; ix = oi; }
      }
      if ((lane & 15) == 0) {
        int token = tb + m * 16 + (lane >> 4) * 4 + r;
        atomicMin(&keys[token], packkey(bd, ix));
      }
    }
}

// ---------- K5: gather emb[idx], straight-through z_q, loss, idx-as-float ----------
__global__ __launch_bounds__(1024)
void kfinal(const unsigned long long* __restrict__ keys,
            const float* __restrict__ zn, const float* __restrict__ embn,
            float* __restrict__ zq, float* __restrict__ loss,
            float* __restrict__ oidx) {
  __shared__ float red[32];
  int t = blockIdx.x * blockDim.x + threadIdx.x;
  int tok = t >> 5, c = t & 31;
  unsigned long long key = keys[tok];
  int idx = (int)(unsigned int)(key & 0xFFFFFFFFull);
  float q = embn[(size_t)idx * DC + c];
  float z = zn[t];
  zq[t] = z + (q - z);
  float d = q - z;
  float ss = d * d;
  #pragma unroll
  for (int m = 16; m >= 1; m >>= 1) ss += __shfl_xor(ss, m, 32);
  if (c == 0) {
    red[threadIdx.x >> 5] = ss;
    oidx[tok] = (float)idx;
  }
  __syncthreads();
  if (threadIdx.x < 32) {
    float v = red[threadIdx.x];
    #pragma unroll
    for (int m = 16; m >= 1; m >>= 1) v += __shfl_xor(v, m, 32);
    if (threadIdx.x == 0)
      atomicAdd(loss, v * (1.0f / (float)(TOKENS * DC)));
  }
}

extern "C" void kernel_launch(void* const* d_in, const int* in_sizes, int n_in,
                              void* d_out, int out_size, void* d_ws, size_t ws_size,
                              hipStream_t stream) {
  const float* X   = (const float*)d_in[0];
  const float* W1  = (const float*)d_in[1];
  const float* B1  = (const float*)d_in[2];
  const float* W2  = (const float*)d_in[3];
  const float* B2  = (const float*)d_in[4];
  const float* CB  = (const float*)d_in[5];

  float* out  = (float*)d_out;
  float* zq   = out;
  float* loss = out + (size_t)TOKENS * DC;
  float* oidx = loss + 1;

  char* ws = (char*)d_ws;
  size_t off = 0;
  _Float16* Hh = (_Float16*)(ws);                                        // 48 MB
  _Float16* Hl = Hh + (size_t)TOKENS * DENC;                             // 48 MB
  off += (size_t)TOKENS * DENC * 4;
  float* zn   = (float*)(ws + off); off += (size_t)TOKENS * DC * 4;      // 4 MB
  float* embn = (float*)(ws + off); off += (size_t)KC * DC * 4;          // 1 MB
  float* se2  = (float*)(ws + off); off += (size_t)KC * 4;               // 32 KB
  _Float16* Eh = (_Float16*)(ws + off); off += (size_t)KC * DC * 2;      // 512 KB
  _Float16* El = (_Float16*)(ws + off); off += (size_t)KC * DC * 2;      // 512 KB
  unsigned long long* keys = (unsigned long long*)(ws + off);
  off += (size_t)TOKENS * 8;                                             // 256 KB
  _Float16* W2h = (_Float16*)(ws + off); off += (size_t)DC * DENC * 2;   // 48 KB
  _Float16* W2l = (_Float16*)(ws + off); off += (size_t)DC * DENC * 2;   // 48 KB
  // W1 split arrays alias the zn region (zn written only by kgemm2, which runs
  // after kgemm1 has consumed W1h/W1l): 2 * 768*768*2B = 2.25 MB < 4 MB.
  _Float16* W1h = (_Float16*)zn;
  _Float16* W1l = W1h + (size_t)DENC * DENC;

  hipMemsetAsync(loss, 0, sizeof(float), stream);
  hipMemsetAsync(keys, 0xFF, (size_t)TOKENS * 8, stream);

  ksplitW<<<dim3(DENC / 256, DENC), 256, 0, stream>>>(W1, W1h, W1l);
  ksplitW2<<<(DENC * DC) / 256, 256, 0, stream>>>(W2, W2h, W2l);
  knorm_codes<<<(KC * DC) / 256, 256, 0, stream>>>(CB, embn, se2, Eh, El);
  kgemm1<<<(TOKENS / BM) * (DENC / BN), 256, 0, stream>>>(X, W1h, W1l, B1, Hh, Hl);
  kgemm2<<<TOKENS / 64, 128, 0, stream>>>(Hh, Hl, W2h, W2l, B2, zn);
  ksearch<<<dim3(TOKENS / 256, KC / 1024), 256, 0, stream>>>(zn, Eh, El, se2, keys);
  kfinal<<<TOKENS * DC / 1024, 1024, 0, stream>>>(keys, zn, embn, zq, loss, oidx);
}

// Round 6
// 297.904 us; speedup vs baseline: 3.7113x; 1.2370x over previous
//
#include <hip/hip_runtime.h>
#include <hip/hip_bf16.h>
#include <cstdint>
#include <cstddef>

// VQKD forward: z = l2norm(tanh(X@W1+b1)@W2+b2); idx = argmin_k ||z-emb_k||^2 with
// emb = l2norm(codebook); z_q = emb[idx]; loss = mean((emb[idx]-z)^2).
// All GEMM-shaped work on f16 matrix cores with 2-way fp32 split (3 products):
// rel error ~3*2^-22 — argmin-safe (validated r3-r5, absmax <= 2.4e-4).

namespace {
constexpr int TOKENS = 8 * 4096;   // 32768
constexpr int DENC   = 768;
constexpr int DC     = 32;
constexpr int KC     = 8192;
constexpr int BM = 128, BN = 128, BK = 32;   // kgemm1 tile (BK=32 -> 64KB dbuf LDS)
constexpr int NSTEP = DENC / BK;             // 24
constexpr float WSCALE = 1024.0f;  // weight split scale (keeps lo out of subnormals)
constexpr float HSCALE = 512.0f;   // H split scale in kgemm2 (2^9 exact)
constexpr float SSCALE = 512.0f;   // z/emb split scale for ksearch (2^9 exact)
constexpr int SCH = 256;           // codes per LDS chunk in ksearch
}

typedef _Float16 f16x8 __attribute__((ext_vector_type(8)));
typedef float    f32x4 __attribute__((ext_vector_type(4)));

__device__ inline void split2(float v, _Float16& h, _Float16& l) {
  h = (_Float16)v;
  l = (_Float16)(v - (float)h);
}

__device__ inline void gload_lds16(const void* g, void* l) {
  __builtin_amdgcn_global_load_lds(
      (const __attribute__((address_space(1))) void*)g,
      (__attribute__((address_space(3))) void*)l, 16, 0, 0);
}

// ---------- K0a: split W1 (x1024) into fp16 hi/lo, TRANSPOSED to [N][K] ----------
__global__ void ksplitW(const float* __restrict__ W1,
                        _Float16* __restrict__ Wh, _Float16* __restrict__ Wl) {
  int n = blockIdx.y;
  int k = blockIdx.x * 256 + threadIdx.x;
  float w = W1[(size_t)k * DENC + n] * WSCALE;
  _Float16 h, l; split2(w, h, l);
  Wh[(size_t)n * DENC + k] = h;
  Wl[(size_t)n * DENC + k] = l;
}

// ---------- K0b: split W2 (x1024) into fp16 hi/lo, TRANSPOSED to [32][768] ----------
__global__ void ksplitW2(const float* __restrict__ W2,
                         _Float16* __restrict__ W2h, _Float16* __restrict__ W2l) {
  int i = blockIdx.x * 256 + threadIdx.x;    // 768*32
  int k = i >> 5, c = i & 31;
  float w = W2[(size_t)k * DC + c] * WSCALE;
  _Float16 h, l; split2(w, h, l);
  W2h[(size_t)c * DENC + k] = h;
  W2l[(size_t)c * DENC + k] = l;
}

// ---------- K1: normalize codebook; emit embn (fp32), split Eh/El (x512), se2 ----------
__global__ void knorm_codes(const float* __restrict__ cb,
                            float* __restrict__ embn, float* __restrict__ se2,
                            _Float16* __restrict__ Eh, _Float16* __restrict__ El) {
  int t = blockIdx.x * blockDim.x + threadIdx.x;
  int k = t >> 5, c = t & 31;
  float v = cb[(size_t)k * DC + c];
  float ss = v * v;
  #pragma unroll
  for (int m = 16; m >= 1; m >>= 1) ss += __shfl_xor(ss, m, 32);
  float nrm = fmaxf(sqrtf(ss), 1e-12f);
  float vn = v / nrm;
  embn[(size_t)k * DC + c] = vn;
  _Float16 h, l; split2(vn * SSCALE, h, l);
  Eh[(size_t)k * DC + c] = h;
  El[(size_t)k * DC + c] = l;
  float s2 = vn * vn;
  #pragma unroll
  for (int m = 16; m >= 1; m >>= 1) s2 += __shfl_xor(s2, m, 32);
  if (c == 0) se2[k] = s2 * (SSCALE * SSCALE);
}

// ---------- K2: H = tanh(X@W1+b1) fp32, MFMA split-2, dbuf LDS, 1 barrier/step ----------
// A: X fp32 -> regs -> split ONCE per block element -> ds_write next buffer (after
// MFMA phase, no race).  B: pre-split W1 planes via global_load_lds direct, issued
// right after the barrier (latency hides under MFMA).  H written fp32 (full lines).
__global__ __launch_bounds__(256, 2)
void kgemm1(const float* __restrict__ X,
            const _Float16* __restrict__ Wh, const _Float16* __restrict__ Wl,
            const float* __restrict__ bias1, float* __restrict__ H) {
  __shared__ __align__(16) _Float16 Ah[2][4][BM][8], Al[2][4][BM][8];  // 16+16 KB
  __shared__ __align__(16) _Float16 Bh[2][4][BN][8], Bl[2][4][BN][8];  // 16+16 KB

  // XCD-aware bijective swizzle (1536 blocks = 8 XCD * 192; 192 = 32 Mt * 6 Nt)
  const int bid = blockIdx.x;
  const int xcd = bid & 7;
  const int w   = bid >> 3;
  const int n_t = w % 6;
  const int m_t = xcd * 32 + w / 6;
  const int m0 = m_t * BM, n0 = n_t * BN;

  const int t    = threadIdx.x;
  const int lane = t & 63;
  const int wv   = t >> 6;
  const int wm   = wv >> 1, wn = wv & 1;
  const int lrow = lane & 15;
  const int lgrp = lane >> 4;

  // A staging role: thread t covers row t>>1, col-half (t&1)*16 (2 k-octets)
  const int arow = t >> 1;
  const int ach  = t & 1;
  const float* xrow = X + (size_t)(m0 + arow) * DENC + ach * 16;

  // B staging role: wave wv stages plane (wv>>1), col-half (wv&1), 4 octets
  const int bpl = wv >> 1, bch = wv & 1;
  const _Float16* wlane = (bpl ? Wl : Wh) + (size_t)(n0 + bch * 64 + lane) * DENC;

  f32x4 acc[4][4];
  #pragma unroll
  for (int i = 0; i < 4; ++i)
    #pragma unroll
    for (int j = 0; j < 4; ++j) acc[i][j] = (f32x4)0.0f;

  // ---- prologue: stage step 0 into buffer 0 ----
  {
    float4 u0 = *(const float4*)(xrow + 0), u1 = *(const float4*)(xrow + 4);
    float4 u2 = *(const float4*)(xrow + 8), u3 = *(const float4*)(xrow + 12);
    float va[16] = {u0.x,u0.y,u0.z,u0.w, u1.x,u1.y,u1.z,u1.w,
                    u2.x,u2.y,u2.z,u2.w, u3.x,u3.y,u3.z,u3.w};
    #pragma unroll
    for (int j = 0; j < 2; ++j) {
      f16x8 hh, ll;
      #pragma unroll
      for (int e = 0; e < 8; ++e) { _Float16 h, l; split2(va[j*8+e], h, l); hh[e]=h; ll[e]=l; }
      *(f16x8*)&Ah[0][ach*2 + j][arow][0] = hh;
      *(f16x8*)&Al[0][ach*2 + j][arow][0] = ll;
    }
    _Float16 (*Bd)[4][BN][8] = bpl ? Bl : Bh;
    #pragma unroll
    for (int o = 0; o < 4; ++o)
      gload_lds16(wlane + o * 8, &Bd[0][o][bch*64 + lane][0]);
  }

  float4 pax[4];
  for (int s = 0; s < NSTEP; ++s) {
    const int cur = s & 1;
    __syncthreads();   // drains vmcnt+lgkm: buf[cur] fully staged

    const bool more = (s + 1 < NSTEP);
    if (more) {
      // issue next A loads (consumed after MFMA phase)
      const float* src = xrow + (s + 1) * BK;
      pax[0] = *(const float4*)(src + 0);  pax[1] = *(const float4*)(src + 4);
      pax[2] = *(const float4*)(src + 8);  pax[3] = *(const float4*)(src + 12);
      // issue next B staging into buf^1 (latency hides under MFMA phase)
      _Float16 (*Bd)[4][BN][8] = bpl ? Bl : Bh;
      const _Float16* wsrc = wlane + (s + 1) * BK;
      #pragma unroll
      for (int o = 0; o < 4; ++o)
        gload_lds16(wsrc + o * 8, &Bd[cur ^ 1][o][bch*64 + lane][0]);
    }

    // ---- MFMA phase on buf[cur] ----
    f16x8 fah[4], fal[4], fbh[4], fbl[4];
    #pragma unroll
    for (int nf = 0; nf < 4; ++nf) {
      const int col = wn * 64 + nf * 16 + lrow;
      fbh[nf] = *(const f16x8*)&Bh[cur][lgrp][col][0];
      fbl[nf] = *(const f16x8*)&Bl[cur][lgrp][col][0];
    }
    #pragma unroll
    for (int mf = 0; mf < 4; ++mf) {
      const int row = wm * 64 + mf * 16 + lrow;
      fah[mf] = *(const f16x8*)&Ah[cur][lgrp][row][0];
      fal[mf] = *(const f16x8*)&Al[cur][lgrp][row][0];
    }
    #pragma unroll
    for (int mf = 0; mf < 4; ++mf)
      #pragma unroll
      for (int nf = 0; nf < 4; ++nf) {
        acc[mf][nf] = __builtin_amdgcn_mfma_f32_16x16x32_f16(fah[mf], fbh[nf], acc[mf][nf], 0, 0, 0);
        acc[mf][nf] = __builtin_amdgcn_mfma_f32_16x16x32_f16(fah[mf], fbl[nf], acc[mf][nf], 0, 0, 0);
        acc[mf][nf] = __builtin_amdgcn_mfma_f32_16x16x32_f16(fal[mf], fbh[nf], acc[mf][nf], 0, 0, 0);
      }

    // ---- split next A and write into buf^1 (short exposed tail) ----
    if (more) {
      float va[16] = {pax[0].x,pax[0].y,pax[0].z,pax[0].w, pax[1].x,pax[1].y,pax[1].z,pax[1].w,
                      pax[2].x,pax[2].y,pax[2].z,pax[2].w, pax[3].x,pax[3].y,pax[3].z,pax[3].w};
      #pragma unroll
      for (int j = 0; j < 2; ++j) {
        f16x8 hh, ll;
        #pragma unroll
        for (int e = 0; e < 8; ++e) { _Float16 h, l; split2(va[j*8+e], h, l); hh[e]=h; ll[e]=l; }
        *(f16x8*)&Ah[cur ^ 1][ach*2 + j][arow][0] = hh;
        *(f16x8*)&Al[cur ^ 1][ach*2 + j][arow][0] = ll;
      }
    }
  }

  // epilogue: un-scale, bias, tanh, store fp32 (4 rows x 64B full lines per store)
  #pragma unroll
  for (int nf = 0; nf < 4; ++nf) {
    const int col = n0 + wn * 64 + nf * 16 + lrow;
    const float b = bias1[col];
    #pragma unroll
    for (int mf = 0; mf < 4; ++mf) {
      #pragma unroll
      for (int r = 0; r < 4; ++r) {
        const int row = m0 + wm * 64 + mf * 16 + lgrp * 4 + r;
        H[(size_t)row * DENC + col] = tanhf(acc[mf][nf][r] * (1.0f / WSCALE) + b);
      }
    }
  }
}

// ---------- K3: zn = l2norm(H @ W2 + b2), MFMA split-2, H split in-register ----------
// No LDS, no barriers. Wave = 32 tokens (2 mf x 2 nf), block = 2 waves.
__global__ __launch_bounds__(128, 4)
void kgemm2(const float* __restrict__ H,
            const _Float16* __restrict__ W2h, const _Float16* __restrict__ W2l,
            const float* __restrict__ b2, float* __restrict__ zn) {
  const int t = threadIdx.x, lane = t & 63, wv = t >> 6;
  const int lrow = lane & 15, lgrp = lane >> 4;
  const int tb = blockIdx.x * 64 + wv * 32;

  const float* ap[2];
  #pragma unroll
  for (int mf = 0; mf < 2; ++mf)
    ap[mf] = H + (size_t)(tb + mf * 16 + lrow) * DENC + lgrp * 8;
  const _Float16* bh_p[2]; const _Float16* bl_p[2];
  #pragma unroll
  for (int nf = 0; nf < 2; ++nf) {
    size_t coff = (size_t)(nf * 16 + lrow) * DENC + lgrp * 8;
    bh_p[nf] = W2h + coff; bl_p[nf] = W2l + coff;
  }

  f32x4 acc[2][2];
  #pragma unroll
  for (int i = 0; i < 2; ++i)
    #pragma unroll
    for (int j = 0; j < 2; ++j) acc[i][j] = (f32x4)0.0f;

  for (int s = 0; s < DENC / 32; ++s) {
    const int koff = s * 32;
    f16x8 a_h[2], a_l[2], b_h[2], b_l[2];
    #pragma unroll
    for (int mf = 0; mf < 2; ++mf) {
      float4 u = *(const float4*)(ap[mf] + koff);
      float4 v = *(const float4*)(ap[mf] + koff + 4);
      float va[8] = {u.x,u.y,u.z,u.w, v.x,v.y,v.z,v.w};
      f16x8 hh, ll;
      #pragma unroll
      for (int e = 0; e < 8; ++e) { _Float16 h, l; split2(va[e] * HSCALE, h, l); hh[e]=h; ll[e]=l; }
      a_h[mf] = hh; a_l[mf] = ll;
    }
    #pragma unroll
    for (int nf = 0; nf < 2; ++nf) {
      b_h[nf] = *(const f16x8*)(bh_p[nf] + koff);
      b_l[nf] = *(const f16x8*)(bl_p[nf] + koff);
    }
    #pragma unroll
    for (int mf = 0; mf < 2; ++mf)
      #pragma unroll
      for (int nf = 0; nf < 2; ++nf) {
        acc[mf][nf] = __builtin_amdgcn_mfma_f32_16x16x32_f16(a_h[mf], b_h[nf], acc[mf][nf], 0, 0, 0);
        acc[mf][nf] = __builtin_amdgcn_mfma_f32_16x16x32_f16(a_h[mf], b_l[nf], acc[mf][nf], 0, 0, 0);
        acc[mf][nf] = __builtin_amdgcn_mfma_f32_16x16x32_f16(a_l[mf], b_h[nf], acc[mf][nf], 0, 0, 0);
      }
  }

  // epilogue: z = acc/2^19 + b2; row-wise l2norm over 32 cols; store zn
  const float inv = 1.0f / (HSCALE * WSCALE);
  float bv[2];
  #pragma unroll
  for (int nf = 0; nf < 2; ++nf) bv[nf] = b2[nf * 16 + lrow];
  #pragma unroll
  for (int mf = 0; mf < 2; ++mf) {
    float z[2][4], ss[4];
    #pragma unroll
    for (int r = 0; r < 4; ++r) {
      #pragma unroll
      for (int nf = 0; nf < 2; ++nf) z[nf][r] = acc[mf][nf][r] * inv + bv[nf];
      float s2 = z[0][r] * z[0][r] + z[1][r] * z[1][r];
      #pragma unroll
      for (int m = 8; m >= 1; m >>= 1) s2 += __shfl_xor(s2, m, 16);
      ss[r] = s2;
    }
    #pragma unroll
    for (int r = 0; r < 4; ++r) {
      const int row = tb + mf * 16 + lgrp * 4 + r;
      float nrm = fmaxf(sqrtf(ss[r]), 1e-12f);
      #pragma unroll
      for (int nf = 0; nf < 2; ++nf)
        zn[(size_t)row * DC + nf * 16 + lrow] = z[nf][r] / nrm;
    }
  }
}

__device__ inline unsigned long long packkey(float d, int idx) {
  unsigned int u = __float_as_uint(d);
  u = (u & 0x80000000u) ? ~u : (u | 0x80000000u);
  return ((unsigned long long)u << 32) | (unsigned int)idx;
}

// ---------- K4: nearest code via MFMA split-2 GEMM + in-register argmin ----------
__global__ __launch_bounds__(256, 3)
void ksearch(const float* __restrict__ zn, const _Float16* __restrict__ Eh,
             const _Float16* __restrict__ El, const float* __restrict__ se2,
             unsigned long long* __restrict__ keys) {
  __shared__ __align__(16) _Float16 Bh[4][SCH][8], Bl[4][SCH][8];  // 32 KB
  __shared__ float ce2[SCH];
  const int t = threadIdx.x, lane = t & 63, wv = t >> 6;
  const int tb  = blockIdx.x * 256 + wv * 64;
  const int cb0 = blockIdx.y * 1024;
  const int lr = lane & 15, ko = lane >> 4;

  f16x8 azh[4], azl[4];
  #pragma unroll
  for (int m = 0; m < 4; ++m) {
    const float* zp = zn + (size_t)(tb + m * 16 + lr) * DC + ko * 8;
    float4 u = *(const float4*)zp, v = *(const float4*)(zp + 4);
    float vals[8] = {u.x, u.y, u.z, u.w, v.x, v.y, v.z, v.w};
    f16x8 hh, ll;
    #pragma unroll
    for (int e = 0; e < 8; ++e) {
      _Float16 h, l; split2(vals[e] * SSCALE, h, l);
      hh[e] = h; ll[e] = l;
    }
    azh[m] = hh; azl[m] = ll;
  }

  float best[4][4]; int bi[4][4];
  #pragma unroll
  for (int m = 0; m < 4; ++m)
    #pragma unroll
    for (int r = 0; r < 4; ++r) { best[m][r] = 3.4e38f; bi[m][r] = 0; }

  f16x8 pb[8]; float pe2;

  for (int ch = 0; ch < 4; ++ch) {
    const int cb = cb0 + ch * SCH;
    #pragma unroll
    for (int it = 0; it < 8; ++it) {
      const _Float16* src = (it < 4) ? Eh : El;
      pb[it] = *(const f16x8*)&src[(size_t)(cb + t) * DC + (it & 3) * 8];
    }
    pe2 = se2[cb + t];
    __syncthreads();
    #pragma unroll
    for (int it = 0; it < 8; ++it) {
      _Float16 (*B)[SCH][8] = (it < 4) ? Bh : Bl;
      *(f16x8*)&B[it & 3][t][0] = pb[it];
    }
    ce2[t] = pe2;
    __syncthreads();

    #pragma unroll 4
    for (int f = 0; f < SCH / 16; ++f) {
      f16x8 bh = *(const f16x8*)&Bh[ko][f * 16 + lr][0];
      f16x8 bl = *(const f16x8*)&Bl[ko][f * 16 + lr][0];
      float e2v = ce2[f * 16 + lr];
      int  code = cb + f * 16 + lr;
      #pragma unroll
      for (int m = 0; m < 4; ++m) {
        f32x4 a = (f32x4)0.0f;
        a = __builtin_amdgcn_mfma_f32_16x16x32_f16(azh[m], bh, a, 0, 0, 0);
        a = __builtin_amdgcn_mfma_f32_16x16x32_f16(azh[m], bl, a, 0, 0, 0);
        a = __builtin_amdgcn_mfma_f32_16x16x32_f16(azl[m], bh, a, 0, 0, 0);
        #pragma unroll
        for (int r = 0; r < 4; ++r) {
          float d = fmaf(-2.0f, a[r], e2v);
          bool c = d < best[m][r];
          best[m][r] = c ? d : best[m][r];
          bi[m][r]   = c ? code : bi[m][r];
        }
      }
    }
  }

  #pragma unroll
  for (int m = 0; m < 4; ++m)
    #pragma unroll
    for (int r = 0; r < 4; ++r) {
      float bd = best[m][r]; int ix = bi[m][r];
      #pragma unroll
      for (int s = 1; s < 16; s <<= 1) {
        float od = __shfl_xor(bd, s);
        int   oi = __shfl_xor(ix, s);
        if (od < bd || (od == bd && oi < ix)) { bd = od; ix = oi; }
      }
      if ((lane & 15) == 0) {
        int token = tb + m * 16 + (lane >> 4) * 4 + r;
        atomicMin(&keys[token], packkey(bd, ix));
      }
    }
}

// ---------- K5: gather emb[idx], straight-through z_q, loss, idx-as-float ----------
__global__ __launch_bounds__(1024)
void kfinal(const unsigned long long* __restrict__ keys,
            const float* __restrict__ zn, const float* __restrict__ embn,
            float* __restrict__ zq, float* __restrict__ loss,
            float* __restrict__ oidx) {
  __shared__ float red[32];
  int t = blockIdx.x * blockDim.x + threadIdx.x;
  int tok = t >> 5, c = t & 31;
  unsigned long long key = keys[tok];
  int idx = (int)(unsigned int)(key & 0xFFFFFFFFull);
  float q = embn[(size_t)idx * DC + c];
  float z = zn[t];
  zq[t] = z + (q - z);
  float d = q - z;
  float ss = d * d;
  #pragma unroll
  for (int m = 16; m >= 1; m >>= 1) ss += __shfl_xor(ss, m, 32);
  if (c == 0) {
    red[threadIdx.x >> 5] = ss;
    oidx[tok] = (float)idx;
  }
  __syncthreads();
  if (threadIdx.x < 32) {
    float v = red[threadIdx.x];
    #pragma unroll
    for (int m = 16; m >= 1; m >>= 1) v += __shfl_xor(v, m, 32);
    if (threadIdx.x == 0)
      atomicAdd(loss, v * (1.0f / (float)(TOKENS * DC)));
  }
}

extern "C" void kernel_launch(void* const* d_in, const int* in_sizes, int n_in,
                              void* d_out, int out_size, void* d_ws, size_t ws_size,
                              hipStream_t stream) {
  const float* X   = (const float*)d_in[0];
  const float* W1  = (const float*)d_in[1];
  const float* B1  = (const float*)d_in[2];
  const float* W2  = (const float*)d_in[3];
  const float* B2  = (const float*)d_in[4];
  const float* CB  = (const float*)d_in[5];

  float* out  = (float*)d_out;
  float* zq   = out;
  float* loss = out + (size_t)TOKENS * DC;
  float* oidx = loss + 1;

  char* ws = (char*)d_ws;
  size_t off = 0;
  float* H    = (float*)(ws + off); off += (size_t)TOKENS * DENC * 4;    // 100.7 MB
  float* zn   = (float*)(ws + off); off += (size_t)TOKENS * DC * 4;      // 4 MB
  float* embn = (float*)(ws + off); off += (size_t)KC * DC * 4;          // 1 MB
  float* se2  = (float*)(ws + off); off += (size_t)KC * 4;               // 32 KB
  _Float16* Eh = (_Float16*)(ws + off); off += (size_t)KC * DC * 2;      // 512 KB
  _Float16* El = (_Float16*)(ws + off); off += (size_t)KC * DC * 2;      // 512 KB
  unsigned long long* keys = (unsigned long long*)(ws + off);
  off += (size_t)TOKENS * 8;                                             // 256 KB
  _Float16* W2h = (_Float16*)(ws + off); off += (size_t)DC * DENC * 2;   // 48 KB
  _Float16* W2l = (_Float16*)(ws + off); off += (size_t)DC * DENC * 2;   // 48 KB
  // W1 split arrays alias the zn region (zn written only by kgemm2, which runs
  // after kgemm1 has consumed W1h/W1l): 2 * 768*768*2B = 2.25 MB < 4 MB.
  _Float16* W1h = (_Float16*)zn;
  _Float16* W1l = W1h + (size_t)DENC * DENC;

  hipMemsetAsync(loss, 0, sizeof(float), stream);
  hipMemsetAsync(keys, 0xFF, (size_t)TOKENS * 8, stream);

  ksplitW<<<dim3(DENC / 256, DENC), 256, 0, stream>>>(W1, W1h, W1l);
  ksplitW2<<<(DENC * DC) / 256, 256, 0, stream>>>(W2, W2h, W2l);
  knorm_codes<<<(KC * DC) / 256, 256, 0, stream>>>(CB, embn, se2, Eh, El);
  kgemm1<<<(TOKENS / BM) * (DENC / BN), 256, 0, stream>>>(X, W1h, W1l, B1, H);
  kgemm2<<<TOKENS / 64, 128, 0, stream>>>(H, W2h, W2l, B2, zn);
  ksearch<<<dim3(TOKENS / 256, KC / 1024), 256, 0, stream>>>(zn, Eh, El, se2, keys);
  kfinal<<<TOKENS * DC / 1024, 1024, 0, stream>>>(keys, zn, embn, zq, loss, oidx);
}